// Round 5
// baseline (2335.397 us; speedup 1.0000x reference)
//
#include <hip/hip_runtime.h>
#include <math.h>

// ---------------------------------------------------------------------------
// Problem constants
// ---------------------------------------------------------------------------
constexpr int B_  = 64;
constexpr int N_  = 197;
constexpr int C_  = 768;
constexpr int H_  = 12;
constexpr int HD_ = 64;
constexpr int NP_ = 40;
constexpr int NK_ = 156;
constexpr int N1_ = 196;
constexpr int N2_ = 157;
constexpr int MLP_ = 3072;
constexpr int M1_ = B_ * N_;    // 12608
constexpr int M2_ = B_ * N2_;   // 10048
constexpr int M1P_ = 12672;     // pad to 128
constexpr int M2P_ = 10112;     // pad to 128
constexpr float SCALE_ = 0.125f;
constexpr float ALPHA_ = 0.1f;
constexpr float EPS_   = 1e-5f;
constexpr int KASC_ATTN = N_ * N_ - 1 - 29106;   // 9702
constexpr int KASC_W    = NK_ * NP_ - 1 - 312;   // 5927
constexpr int NSEG_ = B_ * H_;  // 768

typedef __bf16 bf16x8 __attribute__((ext_vector_type(8)));
typedef float  floatx4 __attribute__((ext_vector_type(4)));

// ---------------------------------------------------------------------------
// Workspace layout (byte offsets) — same envelope as round 3/4 plus ~0.9 MB
// of select state in the smalls region. Total ~215.3 MiB (< proven 235.5 MB).
// ---------------------------------------------------------------------------
constexpr size_t A_B     = 0;
constexpr size_t OFFB_XAHI = A_B;                        // bf16 M1P*C
constexpr size_t OFFB_XALO = A_B + 19464192;             // bf16 M1P*C
constexpr size_t OFFB_ATTN = A_B;                        // fp32 768*197*197
constexpr size_t OFFB_FC1H = A_B;                        // bf16 M2P*3072
constexpr size_t OFFB_H2   = A_B + 62128128;             // bf16 M2P*768
constexpr size_t OFFB_FC1W = A_B + 77660160;             // bf16 3072*768
constexpr size_t OFFB_FC2W = A_B + 82378752;             // bf16 768*3072
constexpr size_t B_B     = 119221248;
constexpr size_t OFFB_QHI  = B_B;                        // bf16 M1P*1536
constexpr size_t OFFB_QLO  = B_B + 38928384;             // bf16 M1P*1536
constexpr size_t OFFB_VB   = B_B + 77856768;             // bf16 M1P*768
constexpr size_t OFFB_X1   = B_B;                        // fp32 M1P*768
constexpr size_t OFFB_AOUT = B_B + 38928384;             // bf16 M1P*768
constexpr size_t OFFB_WBUF = B_B + 77856768;             // fp32 768*156*40
constexpr size_t W_B     = 216542208;
constexpr size_t OFFB_QWHI = W_B;                        // bf16 2304*768
constexpr size_t OFFB_QWLO = W_B + 3538944;
constexpr size_t OFFB_PRJW = W_B + 7077888;              // bf16 768*768
constexpr size_t S_B     = 224799744;
constexpr size_t OFFB_SIG  = S_B;                        // 3072
constexpr size_t OFFB_WSIG = S_B + 3072;                 // 3072
constexpr size_t OFFB_TR   = S_B + 6144;                 // 50176
constexpr size_t OFFB_ORD  = S_B + 56320;                // 50176
constexpr size_t OFFB_HIST = S_B + 106496;               // u32 768*256 = 786432
constexpr size_t OFFB_PFX  = S_B + 892928;               // u32 768
constexpr size_t OFFB_KK   = S_B + 896000;               // i32 768

// ---------------------------------------------------------------------------
// Weight conversion kernels
// ---------------------------------------------------------------------------
__global__ __launch_bounds__(256) void wsplit_kernel(
    const float* __restrict__ w, __bf16* __restrict__ hi,
    __bf16* __restrict__ lo, int n)
{
  const int i = blockIdx.x * 256 + threadIdx.x;
  if (i >= n) return;
  const float v = w[i];
  const __bf16 h = (__bf16)v;
  hi[i] = h;
  lo[i] = (__bf16)(v - (float)h);
}

__global__ __launch_bounds__(256) void wconv_kernel(
    const float* __restrict__ w, __bf16* __restrict__ o, int n)
{
  const int i = blockIdx.x * 256 + threadIdx.x;
  if (i < n) o[i] = (__bf16)w[i];
}

// ---------------------------------------------------------------------------
// Helpers
// ---------------------------------------------------------------------------
__device__ __forceinline__ float block_reduce_sum(float v, float* red) {
  #pragma unroll
  for (int off = 32; off; off >>= 1) v += __shfl_xor(v, off);
  if ((threadIdx.x & 63) == 0) red[threadIdx.x >> 6] = v;
  __syncthreads();
  float r = red[0] + red[1] + red[2] + red[3];
  __syncthreads();
  return r;
}

// ---------------------------------------------------------------------------
// LayerNorm -> bf16 (optionally split hi/lo). Pad rows (>= Mvalid) -> zeros.
// ---------------------------------------------------------------------------
__global__ __launch_bounds__(256) void ln_bf16_kernel(
    const float* __restrict__ x, const float* __restrict__ w,
    const float* __restrict__ b, __bf16* __restrict__ ohi,
    __bf16* __restrict__ olo, int Mvalid)
{
  __shared__ float red[4];
  const size_t row = blockIdx.x;
  const int t = threadIdx.x;
  if ((int)row >= Mvalid) {
    #pragma unroll
    for (int i = 0; i < 3; ++i) {
      ohi[row * C_ + t + 256 * i] = (__bf16)0.f;
      if (olo) olo[row * C_ + t + 256 * i] = (__bf16)0.f;
    }
    return;
  }
  const float* xr = x + row * C_;
  float v[3];
  float s = 0.f;
  #pragma unroll
  for (int i = 0; i < 3; ++i) { v[i] = xr[t + 256 * i]; s += v[i]; }
  const float mu = block_reduce_sum(s, red) * (1.f / 768.f);
  s = 0.f;
  #pragma unroll
  for (int i = 0; i < 3; ++i) { float d = v[i] - mu; s += d * d; }
  const float var = block_reduce_sum(s, red) * (1.f / 768.f);
  const float rs = rsqrtf(var + EPS_);
  #pragma unroll
  for (int i = 0; i < 3; ++i) {
    const int c = t + 256 * i;
    const float val = (v[i] - mu) * rs * w[c] + b[c];
    const __bf16 h = (__bf16)val;
    ohi[row * C_ + c] = h;
    if (olo) olo[row * C_ + c] = (__bf16)(val - (float)h);
  }
}

// ---------------------------------------------------------------------------
// MFMA tile staging: 128x32 bf16 tile, global -> LDS via global_load_lds x16B
// ---------------------------------------------------------------------------
__device__ __forceinline__ void stage_tile(
    const __bf16* __restrict__ gbase, int ldg, __bf16* lds, int wave, int lane)
{
  #pragma unroll
  for (int j = 0; j < 2; ++j) {
    const int seg = 4 * j + wave;
    const int row = seg * 16 + (lane >> 2);
    const int col = (lane & 3) * 8;
    const __bf16* g = gbase + (size_t)row * ldg + col;
    __bf16* l = lds + seg * 512 + lane * 8;
    __builtin_amdgcn_global_load_lds(
        (const __attribute__((address_space(1))) unsigned int*)g,
        (__attribute__((address_space(3))) unsigned int*)l, 16, 0, 0);
  }
}

__device__ __forceinline__ bf16x8 frag(const __bf16* lds, int r, int hi8) {
  return *(const bf16x8*)(lds + r * 32 + hi8);
}

// ---------------------------------------------------------------------------
// Plain bf16 MFMA GEMM: C[m,n] = sum_k A[m,k]*Bw[n,k] (+bias,+gelu,+res)
// ---------------------------------------------------------------------------
__global__ __launch_bounds__(256) void gemm_bf16_kernel(
    const __bf16* __restrict__ A, const __bf16* __restrict__ Bw,
    const float* __restrict__ bias, const float* __restrict__ res,
    float* __restrict__ outf, __bf16* __restrict__ outb,
    int Mstore, int Nn, int K, int act)
{
  __shared__ __bf16 As[128 * 32];
  __shared__ __bf16 Bs[128 * 32];
  const int t = threadIdx.x;
  const int wave = t >> 6, lane = t & 63;
  const int m0 = blockIdx.y * 128, n0 = blockIdx.x * 128;
  const int wm = (wave >> 1) * 64, wn = (wave & 1) * 64;
  const int lo = lane & 15, hi8 = (lane >> 4) * 8;
  floatx4 acc[4][4] = {};
  for (int k0 = 0; k0 < K; k0 += 32) {
    stage_tile(A + (size_t)m0 * K + k0, K, As, wave, lane);
    stage_tile(Bw + (size_t)n0 * K + k0, K, Bs, wave, lane);
    __syncthreads();
    bf16x8 af[4], bfr[4];
    #pragma unroll
    for (int i = 0; i < 4; ++i) af[i]  = frag(As, wm + i * 16 + lo, hi8);
    #pragma unroll
    for (int j = 0; j < 4; ++j) bfr[j] = frag(Bs, wn + j * 16 + lo, hi8);
    #pragma unroll
    for (int i = 0; i < 4; ++i)
      #pragma unroll
      for (int j = 0; j < 4; ++j)
        acc[i][j] = __builtin_amdgcn_mfma_f32_16x16x32_bf16(
            af[i], bfr[j], acc[i][j], 0, 0, 0);
    __syncthreads();
  }
  #pragma unroll
  for (int i = 0; i < 4; ++i) {
    #pragma unroll
    for (int j = 0; j < 4; ++j) {
      #pragma unroll
      for (int r = 0; r < 4; ++r) {
        const int m = m0 + wm + i * 16 + (lane >> 4) * 4 + r;
        const int n = n0 + wn + j * 16 + lo;
        if (m < Mstore) {
          float v = acc[i][j][r];
          if (bias) v += bias[n];
          if (act) v = 0.5f * v * (1.0f + erff(v * 0.7071067811865476f));
          if (res) v += res[(size_t)m * Nn + n];
          if (outf) outf[(size_t)m * Nn + n] = v;
          else      outb[(size_t)m * Nn + n] = (__bf16)v;
        }
      }
    }
  }
}

// ---------------------------------------------------------------------------
// Split-bf16 MFMA GEMM: acc = Ah*Bh + Ah*Bl + Al*Bh; output split hi/lo bf16.
// ---------------------------------------------------------------------------
__global__ __launch_bounds__(256) void gemm_split_kernel(
    const __bf16* __restrict__ Ah, const __bf16* __restrict__ Al,
    const __bf16* __restrict__ Bh, const __bf16* __restrict__ Bl,
    __bf16* __restrict__ outhi, __bf16* __restrict__ outlo, int Nn, int K)
{
  __shared__ __bf16 Ahs[128 * 32];
  __shared__ __bf16 Als[128 * 32];
  __shared__ __bf16 Bhs[128 * 32];
  __shared__ __bf16 Bls[128 * 32];
  const int t = threadIdx.x;
  const int wave = t >> 6, lane = t & 63;
  const int m0 = blockIdx.y * 128, n0 = blockIdx.x * 128;
  const int wm = (wave >> 1) * 64, wn = (wave & 1) * 64;
  const int lo = lane & 15, hi8 = (lane >> 4) * 8;
  floatx4 acc[4][4] = {};
  for (int k0 = 0; k0 < K; k0 += 32) {
    stage_tile(Ah + (size_t)m0 * K + k0, K, Ahs, wave, lane);
    stage_tile(Al + (size_t)m0 * K + k0, K, Als, wave, lane);
    stage_tile(Bh + (size_t)n0 * K + k0, K, Bhs, wave, lane);
    stage_tile(Bl + (size_t)n0 * K + k0, K, Bls, wave, lane);
    __syncthreads();
    bf16x8 ah[4], al[4], bh[4], bl[4];
    #pragma unroll
    for (int i = 0; i < 4; ++i) {
      ah[i] = frag(Ahs, wm + i * 16 + lo, hi8);
      al[i] = frag(Als, wm + i * 16 + lo, hi8);
    }
    #pragma unroll
    for (int j = 0; j < 4; ++j) {
      bh[j] = frag(Bhs, wn + j * 16 + lo, hi8);
      bl[j] = frag(Bls, wn + j * 16 + lo, hi8);
    }
    #pragma unroll
    for (int i = 0; i < 4; ++i)
      #pragma unroll
      for (int j = 0; j < 4; ++j) {
        acc[i][j] = __builtin_amdgcn_mfma_f32_16x16x32_bf16(
            ah[i], bh[j], acc[i][j], 0, 0, 0);
        acc[i][j] = __builtin_amdgcn_mfma_f32_16x16x32_bf16(
            ah[i], bl[j], acc[i][j], 0, 0, 0);
        acc[i][j] = __builtin_amdgcn_mfma_f32_16x16x32_bf16(
            al[i], bh[j], acc[i][j], 0, 0, 0);
      }
    __syncthreads();
  }
  #pragma unroll
  for (int i = 0; i < 4; ++i)
    #pragma unroll
    for (int j = 0; j < 4; ++j)
      #pragma unroll
      for (int r = 0; r < 4; ++r) {
        const int m = m0 + wm + i * 16 + (lane >> 4) * 4 + r;
        const int n = n0 + wn + j * 16 + lo;
        const float v = acc[i][j][r];
        const __bf16 h = (__bf16)v;
        outhi[(size_t)m * Nn + n] = h;
        outlo[(size_t)m * Nn + n] = (__bf16)(v - (float)h);
      }
}

// ---------------------------------------------------------------------------
// Scores via split-bf16 MFMA: per (b,h), S = scale * (Qhi+Qlo)(Khi+Klo)^T.
// ---------------------------------------------------------------------------
__global__ __launch_bounds__(256) void scores_mfma_kernel(
    const __bf16* __restrict__ qhi, const __bf16* __restrict__ qlo,
    float* __restrict__ attn)
{
  const int bh = blockIdx.x;
  const int b = bh / H_, h = bh % H_;
  __shared__ __bf16 Khi[208 * 72];
  __shared__ __bf16 Klo[208 * 72];
  const int t = threadIdx.x;
  for (int idx = t; idx < 208 * 32; idx += 256) {
    const int j = idx >> 5;
    const int c2 = (idx & 31) * 2;
    unsigned int vh = 0u, vl = 0u;
    if (j < N_) {
      const size_t g = ((size_t)(b * N_ + j)) * 1536 + 768 + h * HD_ + c2;
      vh = *(const unsigned int*)(qhi + g);
      vl = *(const unsigned int*)(qlo + g);
    }
    *(unsigned int*)(Khi + j * 72 + c2) = vh;
    *(unsigned int*)(Klo + j * 72 + c2) = vl;
  }
  __syncthreads();
  const int wave = t >> 6, lane = t & 63;
  const int lo16 = lane & 15, k8 = (lane >> 4) * 8;
  float* Sbh = attn + (size_t)bh * N_ * N_;
  bf16x8 zf;
  #pragma unroll
  for (int e = 0; e < 8; ++e) zf[e] = (__bf16)0.f;
  for (int i = 0; i < 4; ++i) {
    const int mrow = wave * 64 + i * 16 + lo16;
    bf16x8 ahi[2], alo[2];
    #pragma unroll
    for (int kk = 0; kk < 2; ++kk) {
      if (mrow < N_) {
        const size_t g = ((size_t)(b * N_ + mrow)) * 1536 + h * HD_ + kk * 32 + k8;
        ahi[kk] = *(const bf16x8*)(qhi + g);
        alo[kk] = *(const bf16x8*)(qlo + g);
      } else {
        ahi[kk] = zf;
        alo[kk] = zf;
      }
    }
    for (int j = 0; j < 13; ++j) {
      floatx4 acc = {0.f, 0.f, 0.f, 0.f};
      #pragma unroll
      for (int kk = 0; kk < 2; ++kk) {
        const bf16x8 bh_ = *(const bf16x8*)(Khi + (j * 16 + lo16) * 72 + kk * 32 + k8);
        const bf16x8 bl_ = *(const bf16x8*)(Klo + (j * 16 + lo16) * 72 + kk * 32 + k8);
        acc = __builtin_amdgcn_mfma_f32_16x16x32_bf16(ahi[kk], bh_, acc, 0, 0, 0);
        acc = __builtin_amdgcn_mfma_f32_16x16x32_bf16(ahi[kk], bl_, acc, 0, 0, 0);
        acc = __builtin_amdgcn_mfma_f32_16x16x32_bf16(alo[kk], bh_, acc, 0, 0, 0);
        acc = __builtin_amdgcn_mfma_f32_16x16x32_bf16(alo[kk], bl_, acc, 0, 0, 0);
      }
      const int col = j * 16 + lo16;
      if (col < N_) {
        #pragma unroll
        for (int r = 0; r < 4; ++r) {
          const int row = wave * 64 + i * 16 + (lane >> 4) * 4 + r;
          if (row < N_) Sbh[(size_t)row * N_ + col] = acc[r] * SCALE_;
        }
      }
    }
  }
}

// ---------------------------------------------------------------------------
// Softmax along last dim (197). One wave per row, 4 rows per block.
// ---------------------------------------------------------------------------
__global__ __launch_bounds__(256) void softmax_kernel(float* __restrict__ attn)
{
  const int row = blockIdx.x * 4 + (threadIdx.x >> 6);
  const int lane = threadIdx.x & 63;
  float* r = attn + (size_t)row * N_;
  float vals[4];
  float m = -1e30f;
  int cnt = 0;
  for (int j = lane; j < N_; j += 64) { vals[cnt] = r[j]; m = fmaxf(m, vals[cnt]); ++cnt; }
  #pragma unroll
  for (int off = 32; off; off >>= 1) m = fmaxf(m, __shfl_xor(m, off));
  float s = 0.f;
  for (int i = 0; i < cnt; ++i) { vals[i] = expf(vals[i] - m); s += vals[i]; }
  #pragma unroll
  for (int off = 32; off; off >>= 1) s += __shfl_xor(s, off);
  const float inv = 1.0f / s;
  cnt = 0;
  for (int j = lane; j < N_; j += 64) { r[j] = vals[cnt] * inv; ++cnt; }
}

// ---------------------------------------------------------------------------
// Parallel exact radix select (k-th smallest ascending per segment).
// State: hist[seg*256], prefix[seg], kk[seg]. 4 passes of 8 bits, MSB first.
// Wave-aggregated LDS atomics (ballot/leader) kill the clustering
// serialization seen as SQ_LDS_BANK_CONFLICT=2.9e7 in the old kernel.
// ---------------------------------------------------------------------------
__global__ __launch_bounds__(256) void rsel_init_kernel(
    unsigned int* __restrict__ hist, unsigned int* __restrict__ prefix,
    int* __restrict__ kk, int k)
{
  const int i = blockIdx.x * 256 + threadIdx.x;
  hist[i] = 0u;                       // grid covers NSEG_*256 exactly
  if (i < NSEG_) { prefix[i] = 0u; kk[i] = k; }
}

__device__ __forceinline__ void wave_agg_inc(
    unsigned int* lh, int bin, bool active)
{
  unsigned long long mask = __ballot(active);
  const int lane = threadIdx.x & 63;
  while (mask) {
    const int leader = __ffsll((unsigned long long)mask) - 1;
    const int lbin = __shfl(bin, leader);
    const unsigned long long match = __ballot(active && (bin == lbin));
    if (lane == leader)
      atomicAdd(&lh[lbin], (unsigned int)__popcll(match));
    mask &= ~match;
  }
}

__global__ __launch_bounds__(256) void rsel_hist_kernel(
    const float* __restrict__ data, int count, int split,
    const unsigned int* __restrict__ prefix, unsigned int* __restrict__ hist,
    int shift)
{
  const int seg = blockIdx.x / split;
  const int sub = blockIdx.x % split;
  const float* sd = data + (size_t)seg * count;
  __shared__ unsigned int lh[256];
  lh[threadIdx.x] = 0u;
  __syncthreads();
  const unsigned int pfx = prefix[seg];
  const unsigned int mask_known =
      (shift == 24) ? 0u : (0xFFFFFFFFu << (shift + 8));
  const int step = split * 256;
  for (int i = sub * 256 + threadIdx.x; i < count; i += step) {
    const unsigned int bits = __float_as_uint(sd[i]);
    const bool act = (bits & mask_known) == pfx;
    const int bin = (bits >> shift) & 0xFF;
    wave_agg_inc(lh, bin, act);
  }
  __syncthreads();
  const unsigned int c = lh[threadIdx.x];
  if (c) atomicAdd(&hist[seg * 256 + threadIdx.x], c);
}

__global__ __launch_bounds__(256) void rsel_scan_kernel(
    unsigned int* __restrict__ hist, unsigned int* __restrict__ prefix,
    int* __restrict__ kk, int shift, float* __restrict__ out)
{
  const int seg = blockIdx.x * 256 + threadIdx.x;
  if (seg >= NSEG_) return;
  unsigned int* h = hist + seg * 256;
  int rem = kk[seg];
  unsigned int d = 255u;
  bool found = false;
  for (int i = 0; i < 256; ++i) {
    const unsigned int c = h[i];
    h[i] = 0u;                        // zero for next pass
    if (!found) {
      if (rem < (int)c) { d = (unsigned int)i; found = true; }
      else rem -= (int)c;
    }
  }
  const unsigned int np = prefix[seg] | (d << shift);
  prefix[seg] = np;
  kk[seg] = rem;
  if (shift == 0 && out) out[seg] = __uint_as_float(np);
}

__global__ __launch_bounds__(256) void threshold_kernel(
    float* __restrict__ a, const float* __restrict__ sig, int total, int seglen)
{
  const int idx = blockIdx.x * 256 + threadIdx.x;
  if (idx >= total) return;
  const float v = a[idx];
  if (v < sig[idx / seglen]) a[idx] = 0.0f;
}

// ---------------------------------------------------------------------------
// attn @ v via bf16 MFMA. Threshold applied during P staging.
// ---------------------------------------------------------------------------
__global__ __launch_bounds__(256) void attn_v_mfma_kernel(
    const float* __restrict__ attn, const float* __restrict__ sig,
    const __bf16* __restrict__ v, __bf16* __restrict__ out)
{
  const int bh = blockIdx.x;
  const int mt = blockIdx.y;
  const int b = bh / H_, h = bh % H_;
  __shared__ __bf16 Ps[64 * 232];
  __shared__ __bf16 Vt[64 * 232];
  const int t = threadIdx.x;
  const float sigbh = sig[bh];
  const float* abase = attn + (size_t)bh * N_ * N_;
  for (int idx = t; idx < 64 * 112; idx += 256) {
    const int r = idx / 112;
    const int j0 = (idx % 112) * 2;
    const int gr = mt * 64 + r;
    float v0 = 0.f, v1 = 0.f;
    if (gr < N_) {
      if (j0 < N_)     { const float a0 = abase[(size_t)gr * N_ + j0];     v0 = (a0 >= sigbh) ? a0 : 0.f; }
      if (j0 + 1 < N_) { const float a1 = abase[(size_t)gr * N_ + j0 + 1]; v1 = (a1 >= sigbh) ? a1 : 0.f; }
    }
    __bf16 p2[2] = {(__bf16)v0, (__bf16)v1};
    *(unsigned int*)(Ps + r * 232 + j0) = *(unsigned int*)p2;
  }
  for (int idx = t; idx < 64 * 224; idx += 256) {
    const int d = idx / 224;
    const int j = idx % 224;
    __bf16 val = (__bf16)0.f;
    if (j < N_) val = v[((size_t)(b * N_ + j)) * C_ + h * HD_ + d];
    Vt[d * 232 + j] = val;
  }
  __syncthreads();
  const int wave = t >> 6, lane = t & 63;
  const int lo16 = lane & 15, k8 = (lane >> 4) * 8;
  #pragma unroll
  for (int jn = 0; jn < 4; ++jn) {
    floatx4 acc = {0.f, 0.f, 0.f, 0.f};
    #pragma unroll
    for (int kk = 0; kk < 7; ++kk) {
      const bf16x8 a = *(const bf16x8*)(Ps + (wave * 16 + lo16) * 232 + kk * 32 + k8);
      const bf16x8 bb = *(const bf16x8*)(Vt + (jn * 16 + lo16) * 232 + kk * 32 + k8);
      acc = __builtin_amdgcn_mfma_f32_16x16x32_bf16(a, bb, acc, 0, 0, 0);
    }
    const int d = jn * 16 + lo16;
    #pragma unroll
    for (int r = 0; r < 4; ++r) {
      const int m = mt * 64 + wave * 16 + (lane >> 4) * 4 + r;
      if (m < N_)
        out[((size_t)b * N_ + m) * C_ + h * HD_ + d] = (__bf16)acc[r];
    }
  }
}

// ---------------------------------------------------------------------------
// token_rank / order / w gather / xprop
// ---------------------------------------------------------------------------
__global__ __launch_bounds__(256) void token_rank_kernel(
    const float* __restrict__ attn, const float* __restrict__ sig,
    float* __restrict__ tr)
{
  const int b = blockIdx.x;
  for (int j = threadIdx.x; j < N1_; j += 256) {
    const int n = j + 1;
    float s = 0.f;
    #pragma unroll
    for (int h = 0; h < H_; ++h) {
      const float d = attn[(((size_t)(b * H_ + h)) * N_ + n) * N_ + n];
      s += (d >= sig[b * H_ + h]) ? d : 0.f;
    }
    tr[b * N1_ + j] = s * (1.f / H_);
  }
}

__global__ __launch_bounds__(256) void order_kernel(
    const float* __restrict__ tr, int* __restrict__ order)
{
  const int b = blockIdx.x;
  __shared__ float v[N1_];
  const int t = threadIdx.x;
  if (t < N1_) v[t] = tr[b * N1_ + t];
  __syncthreads();
  if (t < N1_) {
    const float mv = v[t];
    int r = 0;
    for (int i = 0; i < N1_; ++i) {
      const float vi = v[i];
      r += (vi > mv) || (vi == mv && i < t);
    }
    order[b * N1_ + r] = t;
  }
}

__global__ __launch_bounds__(256) void w_gather_kernel(
    const float* __restrict__ attn, const float* __restrict__ sig,
    const int* __restrict__ ord, float* __restrict__ w)
{
  const int idx = blockIdx.x * 256 + threadIdx.x;
  if (idx >= B_ * H_ * NK_ * NP_) return;
  const int e = idx % NP_;
  const int k = (idx / NP_) % NK_;
  const int h = (idx / (NP_ * NK_)) % H_;
  const int b = idx / (NP_ * NK_ * H_);
  const int ki = ord[b * N1_ + k] + 1;
  const int ej = ord[b * N1_ + NK_ + e] + 1;
  const float v = attn[(((size_t)b * H_ + h) * N_ + ki) * N_ + ej];
  w[idx] = (v >= sig[b * H_ + h]) ? v : 0.f;
}

__global__ __launch_bounds__(256) void xprop_kernel(
    const float* __restrict__ x1, const float* __restrict__ w,
    const int* __restrict__ ord, float* __restrict__ x2)
{
  const int b = blockIdx.y;
  const int kk = blockIdx.x;
  const int t = threadIdx.x;
  if (kk == 0) {
    for (int c = t; c < C_; c += 256)
      x2[(size_t)b * N2_ * C_ + c] = x1[(size_t)b * N_ * C_ + c];
    return;
  }
  const int k = kk - 1;
  __shared__ float ws_[H_ * NP_];
  __shared__ int es[NP_];
  if (t < NP_) es[t] = ord[b * N1_ + NK_ + t] + 1;
  for (int i = t; i < H_ * NP_; i += 256) {
    const int h = i / NP_, e = i % NP_;
    ws_[i] = w[(((size_t)b * H_ + h) * NK_ + k) * NP_ + e];
  }
  __syncthreads();
  const int kept = ord[b * N1_ + k] + 1;
  const float* xk = x1 + ((size_t)b * N_ + kept) * C_;
  float* xo = x2 + ((size_t)b * N2_ + 1 + k) * C_;
  for (int c = t; c < C_; c += 256) {
    const int h = c >> 6;
    float acc = 0.f;
    #pragma unroll 8
    for (int e = 0; e < NP_; ++e)
      acc += ws_[h * NP_ + e] * x1[((size_t)b * N_ + es[e]) * C_ + c];
    xo[c] = xk[c] + ALPHA_ * acc;
  }
}

// ---------------------------------------------------------------------------
// Launcher
// ---------------------------------------------------------------------------
extern "C" void kernel_launch(void* const* d_in, const int* in_sizes, int n_in,
                              void* d_out, int out_size, void* d_ws, size_t ws_size,
                              hipStream_t stream)
{
  const float* x     = (const float*)d_in[0];
  const float* n1w   = (const float*)d_in[1];
  const float* n1b   = (const float*)d_in[2];
  const float* qkvw  = (const float*)d_in[3];
  const float* projw = (const float*)d_in[4];
  const float* projb = (const float*)d_in[5];
  const float* n2w   = (const float*)d_in[6];
  const float* n2b   = (const float*)d_in[7];
  const float* fc1w  = (const float*)d_in[8];
  const float* fc1b  = (const float*)d_in[9];
  const float* fc2w  = (const float*)d_in[10];
  const float* fc2b  = (const float*)d_in[11];
  float* outp = (float*)d_out;

  char* ws = (char*)d_ws;
  __bf16* xa_hi = (__bf16*)(ws + OFFB_XAHI);
  __bf16* xa_lo = (__bf16*)(ws + OFFB_XALO);
  float*  attn  = (float*)(ws + OFFB_ATTN);
  __bf16* fc1h  = (__bf16*)(ws + OFFB_FC1H);
  __bf16* h2    = (__bf16*)(ws + OFFB_H2);
  __bf16* fc1wb = (__bf16*)(ws + OFFB_FC1W);
  __bf16* fc2wb = (__bf16*)(ws + OFFB_FC2W);
  __bf16* qhi   = (__bf16*)(ws + OFFB_QHI);
  __bf16* qlo   = (__bf16*)(ws + OFFB_QLO);
  __bf16* vb    = (__bf16*)(ws + OFFB_VB);
  float*  x1    = (float*)(ws + OFFB_X1);
  __bf16* aout  = (__bf16*)(ws + OFFB_AOUT);
  float*  wbuf  = (float*)(ws + OFFB_WBUF);
  __bf16* qwhi  = (__bf16*)(ws + OFFB_QWHI);
  __bf16* qwlo  = (__bf16*)(ws + OFFB_QWLO);
  __bf16* prjwb = (__bf16*)(ws + OFFB_PRJW);
  float*  sig   = (float*)(ws + OFFB_SIG);
  float*  wsig  = (float*)(ws + OFFB_WSIG);
  float*  tr    = (float*)(ws + OFFB_TR);
  int*    ord   = (int*)(ws + OFFB_ORD);
  unsigned int* hist = (unsigned int*)(ws + OFFB_HIST);
  unsigned int* pfx  = (unsigned int*)(ws + OFFB_PFX);
  int*          kkb  = (int*)(ws + OFFB_KK);
  float*  x2    = outp;

  auto run_select = [&](const float* data, int count, int k, int split,
                        float* out) {
    rsel_init_kernel<<<NSEG_, 256, 0, stream>>>(hist, pfx, kkb, k);
    for (int shift = 24; shift >= 0; shift -= 8) {
      rsel_hist_kernel<<<NSEG_ * split, 256, 0, stream>>>(
          data, count, split, pfx, hist, shift);
      rsel_scan_kernel<<<3, 256, 0, stream>>>(
          hist, pfx, kkb, shift, (shift == 0) ? out : nullptr);
    }
  };

  // Weight conversions needed early
  wsplit_kernel<<<(2304 * 768 + 255) / 256, 256, 0, stream>>>(
      qkvw, qwhi, qwlo, 2304 * 768);
  wconv_kernel<<<(768 * 768 + 255) / 256, 256, 0, stream>>>(
      projw, prjwb, 768 * 768);
  // 1. LN1 -> split bf16 (pad rows zeroed)
  ln_bf16_kernel<<<M1P_, 256, 0, stream>>>(x, n1w, n1b, xa_hi, xa_lo, M1_);
  // 2a. q,k = split GEMM (N=1536) -> hi/lo bf16
  gemm_split_kernel<<<dim3(1536 / 128, M1P_ / 128), 256, 0, stream>>>(
      xa_hi, xa_lo, qwhi, qwlo, qhi, qlo, 1536, C_);
  // 2b. v = plain bf16 GEMM (N=768) -> bf16
  gemm_bf16_kernel<<<dim3(C_ / 128, M1P_ / 128), 256, 0, stream>>>(
      xa_hi, qwhi + (size_t)1536 * C_, nullptr, nullptr, nullptr, vb,
      M1P_, C_, C_, 0);
  // 3. scores via split MFMA (attn overwrites xa region; xa dead)
  scores_mfma_kernel<<<B_ * H_, 256, 0, stream>>>(qhi, qlo, attn);
  // 4. softmax
  softmax_kernel<<<(B_ * H_ * N_) / 4, 256, 0, stream>>>(attn);
  // 5. sigma per (b,h) — parallel wave-aggregated radix select
  run_select(attn, N_ * N_, KASC_ATTN, 8, sig);
  // 6. attn @ v via MFMA (threshold folded into staging) -> aout bf16
  attn_v_mfma_kernel<<<dim3(B_ * H_, 4), 256, 0, stream>>>(attn, sig, vb, aout);
  // 7. token_rank (thresholded diag) + stable order
  token_rank_kernel<<<B_, 256, 0, stream>>>(attn, sig, tr);
  order_kernel<<<B_, 256, 0, stream>>>(tr, ord);
  // 8. x1 = x + aout @ proj_w.T + proj_b (fp32)
  gemm_bf16_kernel<<<dim3(C_ / 128, M1P_ / 128), 256, 0, stream>>>(
      aout, prjwb, projb, x, x1, nullptr, M1_, C_, C_, 0);
  // 9. w gather (threshold folded) + w_sigma + w threshold
  {
    const int total = B_ * H_ * NK_ * NP_;
    w_gather_kernel<<<(total + 255) / 256, 256, 0, stream>>>(attn, sig, ord, wbuf);
    run_select(wbuf, NK_ * NP_, KASC_W, 2, wsig);
    threshold_kernel<<<(total + 255) / 256, 256, 0, stream>>>(wbuf, wsig, total,
                                                              NK_ * NP_);
  }
  // attn now dead -> convert fc1/fc2 weights into tail of region A
  wconv_kernel<<<(MLP_ * C_ + 255) / 256, 256, 0, stream>>>(
      fc1w, fc1wb, MLP_ * C_);
  wconv_kernel<<<(C_ * MLP_ + 255) / 256, 256, 0, stream>>>(
      fc2w, fc2wb, C_ * MLP_);
  // 10. x_prop + assemble x2 (d_out)
  xprop_kernel<<<dim3(N2_, B_), 256, 0, stream>>>(x1, wbuf, ord, x2);
  // 11. LN2 -> bf16 (pad rows zeroed)
  ln_bf16_kernel<<<M2P_, 256, 0, stream>>>(x2, n2w, n2b, h2, nullptr, M2_);
  // 12. fc1 + bias + gelu -> bf16
  gemm_bf16_kernel<<<dim3(MLP_ / 128, M2P_ / 128), 256, 0, stream>>>(
      h2, fc1wb, fc1b, nullptr, nullptr, fc1h, M2P_, MLP_, C_, 1);
  // 13. out = x2 + fc1h @ fc2_w.T + fc2_b (in-place on d_out)
  gemm_bf16_kernel<<<dim3(C_ / 128, M2P_ / 128), 256, 0, stream>>>(
      fc1h, fc2wb, fc2b, x2, outp, nullptr, M2_, C_, MLP_, 0);
}

// Round 6
// 1930.793 us; speedup vs baseline: 1.2096x; 1.2096x over previous
//
#include <hip/hip_runtime.h>
#include <math.h>

// ---------------------------------------------------------------------------
// Problem constants
// ---------------------------------------------------------------------------
constexpr int B_  = 64;
constexpr int N_  = 197;
constexpr int C_  = 768;
constexpr int H_  = 12;
constexpr int HD_ = 64;
constexpr int NP_ = 40;
constexpr int NK_ = 156;
constexpr int N1_ = 196;
constexpr int N2_ = 157;
constexpr int MLP_ = 3072;
constexpr int M1_ = B_ * N_;    // 12608
constexpr int M2_ = B_ * N2_;   // 10048
constexpr int M1P_ = 12672;     // pad to 128
constexpr int M2P_ = 10112;     // pad to 128
constexpr float SCALE_ = 0.125f;
constexpr float ALPHA_ = 0.1f;
constexpr float EPS_   = 1e-5f;
constexpr int KASC_ATTN = N_ * N_ - 1 - 29106;   // 9702
constexpr int KASC_W    = NK_ * NP_ - 1 - 312;   // 5927
constexpr int NSEG_ = B_ * H_;  // 768

typedef __bf16 bf16x8 __attribute__((ext_vector_type(8)));
typedef float  floatx4 __attribute__((ext_vector_type(4)));

// ---------------------------------------------------------------------------
// Workspace layout (byte offsets) — same envelope as rounds 3-5 (~215.3 MiB,
// proven to fit).
// ---------------------------------------------------------------------------
constexpr size_t A_B     = 0;
constexpr size_t OFFB_XAHI = A_B;                        // bf16 M1P*C
constexpr size_t OFFB_XALO = A_B + 19464192;             // bf16 M1P*C
constexpr size_t OFFB_ATTN = A_B;                        // fp32 768*197*197
constexpr size_t OFFB_FC1H = A_B;                        // bf16 M2P*3072
constexpr size_t OFFB_H2   = A_B + 62128128;             // bf16 M2P*768
constexpr size_t OFFB_FC1W = A_B + 77660160;             // bf16 3072*768
constexpr size_t OFFB_FC2W = A_B + 82378752;             // bf16 768*3072
constexpr size_t B_B     = 119221248;
constexpr size_t OFFB_QHI  = B_B;                        // bf16 M1P*1536
constexpr size_t OFFB_QLO  = B_B + 38928384;             // bf16 M1P*1536
constexpr size_t OFFB_VB   = B_B + 77856768;             // bf16 M1P*768
constexpr size_t OFFB_X1   = B_B;                        // fp32 M1P*768
constexpr size_t OFFB_AOUT = B_B + 38928384;             // bf16 M1P*768
constexpr size_t OFFB_WBUF = B_B + 77856768;             // fp32 768*156*40
constexpr size_t W_B     = 216542208;
constexpr size_t OFFB_QWHI = W_B;                        // bf16 2304*768
constexpr size_t OFFB_QWLO = W_B + 3538944;
constexpr size_t OFFB_PRJW = W_B + 7077888;              // bf16 768*768
constexpr size_t S_B     = 224799744;
constexpr size_t OFFB_SIG  = S_B;                        // 3072
constexpr size_t OFFB_WSIG = S_B + 3072;                 // 3072
constexpr size_t OFFB_TR   = S_B + 6144;                 // 50176
constexpr size_t OFFB_ORD  = S_B + 56320;                // 50176
constexpr size_t OFFB_HIST = S_B + 106496;               // u32 768*256 = 786432
constexpr size_t OFFB_PFX  = S_B + 892928;               // u32 768
constexpr size_t OFFB_KK   = S_B + 896000;               // i32 768

// ---------------------------------------------------------------------------
// Weight conversion kernels
// ---------------------------------------------------------------------------
__global__ __launch_bounds__(256) void wsplit_kernel(
    const float* __restrict__ w, __bf16* __restrict__ hi,
    __bf16* __restrict__ lo, int n)
{
  const int i = blockIdx.x * 256 + threadIdx.x;
  if (i >= n) return;
  const float v = w[i];
  const __bf16 h = (__bf16)v;
  hi[i] = h;
  lo[i] = (__bf16)(v - (float)h);
}

__global__ __launch_bounds__(256) void wconv_kernel(
    const float* __restrict__ w, __bf16* __restrict__ o, int n)
{
  const int i = blockIdx.x * 256 + threadIdx.x;
  if (i < n) o[i] = (__bf16)w[i];
}

// ---------------------------------------------------------------------------
// Helpers
// ---------------------------------------------------------------------------
__device__ __forceinline__ float block_reduce_sum(float v, float* red) {
  #pragma unroll
  for (int off = 32; off; off >>= 1) v += __shfl_xor(v, off);
  if ((threadIdx.x & 63) == 0) red[threadIdx.x >> 6] = v;
  __syncthreads();
  float r = red[0] + red[1] + red[2] + red[3];
  __syncthreads();
  return r;
}

// ---------------------------------------------------------------------------
// LayerNorm -> bf16 (optionally split hi/lo). Pad rows (>= Mvalid) -> zeros.
// ---------------------------------------------------------------------------
__global__ __launch_bounds__(256) void ln_bf16_kernel(
    const float* __restrict__ x, const float* __restrict__ w,
    const float* __restrict__ b, __bf16* __restrict__ ohi,
    __bf16* __restrict__ olo, int Mvalid)
{
  __shared__ float red[4];
  const size_t row = blockIdx.x;
  const int t = threadIdx.x;
  if ((int)row >= Mvalid) {
    #pragma unroll
    for (int i = 0; i < 3; ++i) {
      ohi[row * C_ + t + 256 * i] = (__bf16)0.f;
      if (olo) olo[row * C_ + t + 256 * i] = (__bf16)0.f;
    }
    return;
  }
  const float* xr = x + row * C_;
  float v[3];
  float s = 0.f;
  #pragma unroll
  for (int i = 0; i < 3; ++i) { v[i] = xr[t + 256 * i]; s += v[i]; }
  const float mu = block_reduce_sum(s, red) * (1.f / 768.f);
  s = 0.f;
  #pragma unroll
  for (int i = 0; i < 3; ++i) { float d = v[i] - mu; s += d * d; }
  const float var = block_reduce_sum(s, red) * (1.f / 768.f);
  const float rs = rsqrtf(var + EPS_);
  #pragma unroll
  for (int i = 0; i < 3; ++i) {
    const int c = t + 256 * i;
    const float val = (v[i] - mu) * rs * w[c] + b[c];
    const __bf16 h = (__bf16)val;
    ohi[row * C_ + c] = h;
    if (olo) olo[row * C_ + c] = (__bf16)(val - (float)h);
  }
}

// ---------------------------------------------------------------------------
// MFMA tile staging: 128x32 bf16 tile, global -> LDS via global_load_lds x16B
// ---------------------------------------------------------------------------
__device__ __forceinline__ void stage_tile(
    const __bf16* __restrict__ gbase, int ldg, __bf16* lds, int wave, int lane)
{
  #pragma unroll
  for (int j = 0; j < 2; ++j) {
    const int seg = 4 * j + wave;
    const int row = seg * 16 + (lane >> 2);
    const int col = (lane & 3) * 8;
    const __bf16* g = gbase + (size_t)row * ldg + col;
    __bf16* l = lds + seg * 512 + lane * 8;
    __builtin_amdgcn_global_load_lds(
        (const __attribute__((address_space(1))) unsigned int*)g,
        (__attribute__((address_space(3))) unsigned int*)l, 16, 0, 0);
  }
}

__device__ __forceinline__ bf16x8 frag(const __bf16* lds, int r, int hi8) {
  return *(const bf16x8*)(lds + r * 32 + hi8);
}

// ---------------------------------------------------------------------------
// Plain bf16 MFMA GEMM: C[m,n] = sum_k A[m,k]*Bw[n,k] (+bias,+gelu,+res)
// ---------------------------------------------------------------------------
__global__ __launch_bounds__(256) void gemm_bf16_kernel(
    const __bf16* __restrict__ A, const __bf16* __restrict__ Bw,
    const float* __restrict__ bias, const float* __restrict__ res,
    float* __restrict__ outf, __bf16* __restrict__ outb,
    int Mstore, int Nn, int K, int act)
{
  __shared__ __bf16 As[128 * 32];
  __shared__ __bf16 Bs[128 * 32];
  const int t = threadIdx.x;
  const int wave = t >> 6, lane = t & 63;
  const int m0 = blockIdx.y * 128, n0 = blockIdx.x * 128;
  const int wm = (wave >> 1) * 64, wn = (wave & 1) * 64;
  const int lo = lane & 15, hi8 = (lane >> 4) * 8;
  floatx4 acc[4][4] = {};
  for (int k0 = 0; k0 < K; k0 += 32) {
    stage_tile(A + (size_t)m0 * K + k0, K, As, wave, lane);
    stage_tile(Bw + (size_t)n0 * K + k0, K, Bs, wave, lane);
    __syncthreads();
    bf16x8 af[4], bfr[4];
    #pragma unroll
    for (int i = 0; i < 4; ++i) af[i]  = frag(As, wm + i * 16 + lo, hi8);
    #pragma unroll
    for (int j = 0; j < 4; ++j) bfr[j] = frag(Bs, wn + j * 16 + lo, hi8);
    #pragma unroll
    for (int i = 0; i < 4; ++i)
      #pragma unroll
      for (int j = 0; j < 4; ++j)
        acc[i][j] = __builtin_amdgcn_mfma_f32_16x16x32_bf16(
            af[i], bfr[j], acc[i][j], 0, 0, 0);
    __syncthreads();
  }
  #pragma unroll
  for (int i = 0; i < 4; ++i) {
    #pragma unroll
    for (int j = 0; j < 4; ++j) {
      #pragma unroll
      for (int r = 0; r < 4; ++r) {
        const int m = m0 + wm + i * 16 + (lane >> 4) * 4 + r;
        const int n = n0 + wn + j * 16 + lo;
        if (m < Mstore) {
          float v = acc[i][j][r];
          if (bias) v += bias[n];
          if (act) v = 0.5f * v * (1.0f + erff(v * 0.7071067811865476f));
          if (res) v += res[(size_t)m * Nn + n];
          if (outf) outf[(size_t)m * Nn + n] = v;
          else      outb[(size_t)m * Nn + n] = (__bf16)v;
        }
      }
    }
  }
}

// ---------------------------------------------------------------------------
// Split-bf16 MFMA GEMM: acc = Ah*Bh + Ah*Bl + Al*Bh; output split hi/lo bf16.
// ---------------------------------------------------------------------------
__global__ __launch_bounds__(256) void gemm_split_kernel(
    const __bf16* __restrict__ Ah, const __bf16* __restrict__ Al,
    const __bf16* __restrict__ Bh, const __bf16* __restrict__ Bl,
    __bf16* __restrict__ outhi, __bf16* __restrict__ outlo, int Nn, int K)
{
  __shared__ __bf16 Ahs[128 * 32];
  __shared__ __bf16 Als[128 * 32];
  __shared__ __bf16 Bhs[128 * 32];
  __shared__ __bf16 Bls[128 * 32];
  const int t = threadIdx.x;
  const int wave = t >> 6, lane = t & 63;
  const int m0 = blockIdx.y * 128, n0 = blockIdx.x * 128;
  const int wm = (wave >> 1) * 64, wn = (wave & 1) * 64;
  const int lo = lane & 15, hi8 = (lane >> 4) * 8;
  floatx4 acc[4][4] = {};
  for (int k0 = 0; k0 < K; k0 += 32) {
    stage_tile(Ah + (size_t)m0 * K + k0, K, Ahs, wave, lane);
    stage_tile(Al + (size_t)m0 * K + k0, K, Als, wave, lane);
    stage_tile(Bh + (size_t)n0 * K + k0, K, Bhs, wave, lane);
    stage_tile(Bl + (size_t)n0 * K + k0, K, Bls, wave, lane);
    __syncthreads();
    bf16x8 ah[4], al[4], bh[4], bl[4];
    #pragma unroll
    for (int i = 0; i < 4; ++i) {
      ah[i] = frag(Ahs, wm + i * 16 + lo, hi8);
      al[i] = frag(Als, wm + i * 16 + lo, hi8);
    }
    #pragma unroll
    for (int j = 0; j < 4; ++j) {
      bh[j] = frag(Bhs, wn + j * 16 + lo, hi8);
      bl[j] = frag(Bls, wn + j * 16 + lo, hi8);
    }
    #pragma unroll
    for (int i = 0; i < 4; ++i)
      #pragma unroll
      for (int j = 0; j < 4; ++j) {
        acc[i][j] = __builtin_amdgcn_mfma_f32_16x16x32_bf16(
            ah[i], bh[j], acc[i][j], 0, 0, 0);
        acc[i][j] = __builtin_amdgcn_mfma_f32_16x16x32_bf16(
            ah[i], bl[j], acc[i][j], 0, 0, 0);
        acc[i][j] = __builtin_amdgcn_mfma_f32_16x16x32_bf16(
            al[i], bh[j], acc[i][j], 0, 0, 0);
      }
    __syncthreads();
  }
  #pragma unroll
  for (int i = 0; i < 4; ++i)
    #pragma unroll
    for (int j = 0; j < 4; ++j)
      #pragma unroll
      for (int r = 0; r < 4; ++r) {
        const int m = m0 + wm + i * 16 + (lane >> 4) * 4 + r;
        const int n = n0 + wn + j * 16 + lo;
        const float v = acc[i][j][r];
        const __bf16 h = (__bf16)v;
        outhi[(size_t)m * Nn + n] = h;
        outlo[(size_t)m * Nn + n] = (__bf16)(v - (float)h);
      }
}

// ---------------------------------------------------------------------------
// Scores via split-bf16 MFMA: per (b,h), S = scale * (Qhi+Qlo)(Khi+Klo)^T.
// ---------------------------------------------------------------------------
__global__ __launch_bounds__(256) void scores_mfma_kernel(
    const __bf16* __restrict__ qhi, const __bf16* __restrict__ qlo,
    float* __restrict__ attn)
{
  const int bh = blockIdx.x;
  const int b = bh / H_, h = bh % H_;
  __shared__ __bf16 Khi[208 * 72];
  __shared__ __bf16 Klo[208 * 72];
  const int t = threadIdx.x;
  for (int idx = t; idx < 208 * 32; idx += 256) {
    const int j = idx >> 5;
    const int c2 = (idx & 31) * 2;
    unsigned int vh = 0u, vl = 0u;
    if (j < N_) {
      const size_t g = ((size_t)(b * N_ + j)) * 1536 + 768 + h * HD_ + c2;
      vh = *(const unsigned int*)(qhi + g);
      vl = *(const unsigned int*)(qlo + g);
    }
    *(unsigned int*)(Khi + j * 72 + c2) = vh;
    *(unsigned int*)(Klo + j * 72 + c2) = vl;
  }
  __syncthreads();
  const int wave = t >> 6, lane = t & 63;
  const int lo16 = lane & 15, k8 = (lane >> 4) * 8;
  float* Sbh = attn + (size_t)bh * N_ * N_;
  bf16x8 zf;
  #pragma unroll
  for (int e = 0; e < 8; ++e) zf[e] = (__bf16)0.f;
  for (int i = 0; i < 4; ++i) {
    const int mrow = wave * 64 + i * 16 + lo16;
    bf16x8 ahi[2], alo[2];
    #pragma unroll
    for (int kk = 0; kk < 2; ++kk) {
      if (mrow < N_) {
        const size_t g = ((size_t)(b * N_ + mrow)) * 1536 + h * HD_ + kk * 32 + k8;
        ahi[kk] = *(const bf16x8*)(qhi + g);
        alo[kk] = *(const bf16x8*)(qlo + g);
      } else {
        ahi[kk] = zf;
        alo[kk] = zf;
      }
    }
    for (int j = 0; j < 13; ++j) {
      floatx4 acc = {0.f, 0.f, 0.f, 0.f};
      #pragma unroll
      for (int kk = 0; kk < 2; ++kk) {
        const bf16x8 bh_ = *(const bf16x8*)(Khi + (j * 16 + lo16) * 72 + kk * 32 + k8);
        const bf16x8 bl_ = *(const bf16x8*)(Klo + (j * 16 + lo16) * 72 + kk * 32 + k8);
        acc = __builtin_amdgcn_mfma_f32_16x16x32_bf16(ahi[kk], bh_, acc, 0, 0, 0);
        acc = __builtin_amdgcn_mfma_f32_16x16x32_bf16(ahi[kk], bl_, acc, 0, 0, 0);
        acc = __builtin_amdgcn_mfma_f32_16x16x32_bf16(alo[kk], bh_, acc, 0, 0, 0);
        acc = __builtin_amdgcn_mfma_f32_16x16x32_bf16(alo[kk], bl_, acc, 0, 0, 0);
      }
      const int col = j * 16 + lo16;
      if (col < N_) {
        #pragma unroll
        for (int r = 0; r < 4; ++r) {
          const int row = wave * 64 + i * 16 + (lane >> 4) * 4 + r;
          if (row < N_) Sbh[(size_t)row * N_ + col] = acc[r] * SCALE_;
        }
      }
    }
  }
}

// ---------------------------------------------------------------------------
// Softmax along last dim (197). One wave per row, 4 rows per block.
// ---------------------------------------------------------------------------
__global__ __launch_bounds__(256) void softmax_kernel(float* __restrict__ attn)
{
  const int row = blockIdx.x * 4 + (threadIdx.x >> 6);
  const int lane = threadIdx.x & 63;
  float* r = attn + (size_t)row * N_;
  float vals[4];
  float m = -1e30f;
  int cnt = 0;
  for (int j = lane; j < N_; j += 64) { vals[cnt] = r[j]; m = fmaxf(m, vals[cnt]); ++cnt; }
  #pragma unroll
  for (int off = 32; off; off >>= 1) m = fmaxf(m, __shfl_xor(m, off));
  float s = 0.f;
  for (int i = 0; i < cnt; ++i) { vals[i] = expf(vals[i] - m); s += vals[i]; }
  #pragma unroll
  for (int off = 32; off; off >>= 1) s += __shfl_xor(s, off);
  const float inv = 1.0f / s;
  cnt = 0;
  for (int j = lane; j < N_; j += 64) { r[j] = vals[cnt] * inv; ++cnt; }
}

// ---------------------------------------------------------------------------
// Parallel exact radix select (k-th smallest ascending per segment).
// Split grid for parallelism; plain predicated LDS atomics (HW-serialized,
// worst 64-way — cheap; the round-5 ballot loop was the real cost).
// ---------------------------------------------------------------------------
__global__ __launch_bounds__(256) void rsel_init_kernel(
    unsigned int* __restrict__ hist, unsigned int* __restrict__ prefix,
    int* __restrict__ kk, int k)
{
  const int i = blockIdx.x * 256 + threadIdx.x;
  hist[i] = 0u;                       // grid covers NSEG_*256 exactly
  if (i < NSEG_) { prefix[i] = 0u; kk[i] = k; }
}

__global__ __launch_bounds__(256) void rsel_hist_kernel(
    const float* __restrict__ data, int count, int split,
    const unsigned int* __restrict__ prefix, unsigned int* __restrict__ hist,
    int shift)
{
  const int seg = blockIdx.x / split;
  const int sub = blockIdx.x % split;
  const float* sd = data + (size_t)seg * count;
  __shared__ unsigned int lh[256];
  lh[threadIdx.x] = 0u;
  __syncthreads();
  const unsigned int pfx = prefix[seg];
  const unsigned int mask_known =
      (shift == 24) ? 0u : (0xFFFFFFFFu << (shift + 8));
  const int step = split * 256;
  for (int i = sub * 256 + threadIdx.x; i < count; i += step) {
    const unsigned int bits = __float_as_uint(sd[i]);
    if ((bits & mask_known) == pfx)
      atomicAdd(&lh[(bits >> shift) & 0xFFu], 1u);
  }
  __syncthreads();
  const unsigned int c = lh[threadIdx.x];
  if (c) atomicAdd(&hist[seg * 256 + threadIdx.x], c);
}

__global__ __launch_bounds__(256) void rsel_scan_kernel(
    unsigned int* __restrict__ hist, unsigned int* __restrict__ prefix,
    int* __restrict__ kk, int shift, float* __restrict__ out)
{
  const int seg = blockIdx.x * 256 + threadIdx.x;
  if (seg >= NSEG_) return;
  unsigned int* h = hist + seg * 256;
  int rem = kk[seg];
  unsigned int d = 255u;
  bool found = false;
  for (int i = 0; i < 256; ++i) {
    const unsigned int c = h[i];
    h[i] = 0u;                        // zero for next pass
    if (!found) {
      if (rem < (int)c) { d = (unsigned int)i; found = true; }
      else rem -= (int)c;
    }
  }
  const unsigned int np = prefix[seg] | (d << shift);
  prefix[seg] = np;
  kk[seg] = rem;
  if (shift == 0 && out) out[seg] = __uint_as_float(np);
}

__global__ __launch_bounds__(256) void threshold_kernel(
    float* __restrict__ a, const float* __restrict__ sig, int total, int seglen)
{
  const int idx = blockIdx.x * 256 + threadIdx.x;
  if (idx >= total) return;
  const float v = a[idx];
  if (v < sig[idx / seglen]) a[idx] = 0.0f;
}

// ---------------------------------------------------------------------------
// attn @ v via bf16 MFMA. Threshold applied during P staging.
// ---------------------------------------------------------------------------
__global__ __launch_bounds__(256) void attn_v_mfma_kernel(
    const float* __restrict__ attn, const float* __restrict__ sig,
    const __bf16* __restrict__ v, __bf16* __restrict__ out)
{
  const int bh = blockIdx.x;
  const int mt = blockIdx.y;
  const int b = bh / H_, h = bh % H_;
  __shared__ __bf16 Ps[64 * 232];
  __shared__ __bf16 Vt[64 * 232];
  const int t = threadIdx.x;
  const float sigbh = sig[bh];
  const float* abase = attn + (size_t)bh * N_ * N_;
  for (int idx = t; idx < 64 * 112; idx += 256) {
    const int r = idx / 112;
    const int j0 = (idx % 112) * 2;
    const int gr = mt * 64 + r;
    float v0 = 0.f, v1 = 0.f;
    if (gr < N_) {
      if (j0 < N_)     { const float a0 = abase[(size_t)gr * N_ + j0];     v0 = (a0 >= sigbh) ? a0 : 0.f; }
      if (j0 + 1 < N_) { const float a1 = abase[(size_t)gr * N_ + j0 + 1]; v1 = (a1 >= sigbh) ? a1 : 0.f; }
    }
    __bf16 p2[2] = {(__bf16)v0, (__bf16)v1};
    *(unsigned int*)(Ps + r * 232 + j0) = *(unsigned int*)p2;
  }
  for (int idx = t; idx < 64 * 224; idx += 256) {
    const int d = idx / 224;
    const int j = idx % 224;
    __bf16 val = (__bf16)0.f;
    if (j < N_) val = v[((size_t)(b * N_ + j)) * C_ + h * HD_ + d];
    Vt[d * 232 + j] = val;
  }
  __syncthreads();
  const int wave = t >> 6, lane = t & 63;
  const int lo16 = lane & 15, k8 = (lane >> 4) * 8;
  #pragma unroll
  for (int jn = 0; jn < 4; ++jn) {
    floatx4 acc = {0.f, 0.f, 0.f, 0.f};
    #pragma unroll
    for (int kk = 0; kk < 7; ++kk) {
      const bf16x8 a = *(const bf16x8*)(Ps + (wave * 16 + lo16) * 232 + kk * 32 + k8);
      const bf16x8 bb = *(const bf16x8*)(Vt + (jn * 16 + lo16) * 232 + kk * 32 + k8);
      acc = __builtin_amdgcn_mfma_f32_16x16x32_bf16(a, bb, acc, 0, 0, 0);
    }
    const int d = jn * 16 + lo16;
    #pragma unroll
    for (int r = 0; r < 4; ++r) {
      const int m = mt * 64 + wave * 16 + (lane >> 4) * 4 + r;
      if (m < N_)
        out[((size_t)b * N_ + m) * C_ + h * HD_ + d] = (__bf16)acc[r];
    }
  }
}

// ---------------------------------------------------------------------------
// token_rank / order / w gather / xprop
// ---------------------------------------------------------------------------
__global__ __launch_bounds__(256) void token_rank_kernel(
    const float* __restrict__ attn, const float* __restrict__ sig,
    float* __restrict__ tr)
{
  const int b = blockIdx.x;
  for (int j = threadIdx.x; j < N1_; j += 256) {
    const int n = j + 1;
    float s = 0.f;
    #pragma unroll
    for (int h = 0; h < H_; ++h) {
      const float d = attn[(((size_t)(b * H_ + h)) * N_ + n) * N_ + n];
      s += (d >= sig[b * H_ + h]) ? d : 0.f;
    }
    tr[b * N1_ + j] = s * (1.f / H_);
  }
}

__global__ __launch_bounds__(256) void order_kernel(
    const float* __restrict__ tr, int* __restrict__ order)
{
  const int b = blockIdx.x;
  __shared__ float v[N1_];
  const int t = threadIdx.x;
  if (t < N1_) v[t] = tr[b * N1_ + t];
  __syncthreads();
  if (t < N1_) {
    const float mv = v[t];
    int r = 0;
    for (int i = 0; i < N1_; ++i) {
      const float vi = v[i];
      r += (vi > mv) || (vi == mv && i < t);
    }
    order[b * N1_ + r] = t;
  }
}

__global__ __launch_bounds__(256) void w_gather_kernel(
    const float* __restrict__ attn, const float* __restrict__ sig,
    const int* __restrict__ ord, float* __restrict__ w)
{
  const int idx = blockIdx.x * 256 + threadIdx.x;
  if (idx >= B_ * H_ * NK_ * NP_) return;
  const int e = idx % NP_;
  const int k = (idx / NP_) % NK_;
  const int h = (idx / (NP_ * NK_)) % H_;
  const int b = idx / (NP_ * NK_ * H_);
  const int ki = ord[b * N1_ + k] + 1;
  const int ej = ord[b * N1_ + NK_ + e] + 1;
  const float v = attn[(((size_t)b * H_ + h) * N_ + ki) * N_ + ej];
  w[idx] = (v >= sig[b * H_ + h]) ? v : 0.f;
}

__global__ __launch_bounds__(256) void xprop_kernel(
    const float* __restrict__ x1, const float* __restrict__ w,
    const int* __restrict__ ord, float* __restrict__ x2)
{
  const int b = blockIdx.y;
  const int kk = blockIdx.x;
  const int t = threadIdx.x;
  if (kk == 0) {
    for (int c = t; c < C_; c += 256)
      x2[(size_t)b * N2_ * C_ + c] = x1[(size_t)b * N_ * C_ + c];
    return;
  }
  const int k = kk - 1;
  __shared__ float ws_[H_ * NP_];
  __shared__ int es[NP_];
  if (t < NP_) es[t] = ord[b * N1_ + NK_ + t] + 1;
  for (int i = t; i < H_ * NP_; i += 256) {
    const int h = i / NP_, e = i % NP_;
    ws_[i] = w[(((size_t)b * H_ + h) * NK_ + k) * NP_ + e];
  }
  __syncthreads();
  const int kept = ord[b * N1_ + k] + 1;
  const float* xk = x1 + ((size_t)b * N_ + kept) * C_;
  float* xo = x2 + ((size_t)b * N2_ + 1 + k) * C_;
  for (int c = t; c < C_; c += 256) {
    const int h = c >> 6;
    float acc = 0.f;
    #pragma unroll 8
    for (int e = 0; e < NP_; ++e)
      acc += ws_[h * NP_ + e] * x1[((size_t)b * N_ + es[e]) * C_ + c];
    xo[c] = xk[c] + ALPHA_ * acc;
  }
}

// ---------------------------------------------------------------------------
// Launcher
// ---------------------------------------------------------------------------
extern "C" void kernel_launch(void* const* d_in, const int* in_sizes, int n_in,
                              void* d_out, int out_size, void* d_ws, size_t ws_size,
                              hipStream_t stream)
{
  const float* x     = (const float*)d_in[0];
  const float* n1w   = (const float*)d_in[1];
  const float* n1b   = (const float*)d_in[2];
  const float* qkvw  = (const float*)d_in[3];
  const float* projw = (const float*)d_in[4];
  const float* projb = (const float*)d_in[5];
  const float* n2w   = (const float*)d_in[6];
  const float* n2b   = (const float*)d_in[7];
  const float* fc1w  = (const float*)d_in[8];
  const float* fc1b  = (const float*)d_in[9];
  const float* fc2w  = (const float*)d_in[10];
  const float* fc2b  = (const float*)d_in[11];
  float* outp = (float*)d_out;

  char* ws = (char*)d_ws;
  __bf16* xa_hi = (__bf16*)(ws + OFFB_XAHI);
  __bf16* xa_lo = (__bf16*)(ws + OFFB_XALO);
  float*  attn  = (float*)(ws + OFFB_ATTN);
  __bf16* fc1h  = (__bf16*)(ws + OFFB_FC1H);
  __bf16* h2    = (__bf16*)(ws + OFFB_H2);
  __bf16* fc1wb = (__bf16*)(ws + OFFB_FC1W);
  __bf16* fc2wb = (__bf16*)(ws + OFFB_FC2W);
  __bf16* qhi   = (__bf16*)(ws + OFFB_QHI);
  __bf16* qlo   = (__bf16*)(ws + OFFB_QLO);
  __bf16* vb    = (__bf16*)(ws + OFFB_VB);
  float*  x1    = (float*)(ws + OFFB_X1);
  __bf16* aout  = (__bf16*)(ws + OFFB_AOUT);
  float*  wbuf  = (float*)(ws + OFFB_WBUF);
  __bf16* qwhi  = (__bf16*)(ws + OFFB_QWHI);
  __bf16* qwlo  = (__bf16*)(ws + OFFB_QWLO);
  __bf16* prjwb = (__bf16*)(ws + OFFB_PRJW);
  float*  sig   = (float*)(ws + OFFB_SIG);
  float*  wsig  = (float*)(ws + OFFB_WSIG);
  float*  tr    = (float*)(ws + OFFB_TR);
  int*    ord   = (int*)(ws + OFFB_ORD);
  unsigned int* hist = (unsigned int*)(ws + OFFB_HIST);
  unsigned int* pfx  = (unsigned int*)(ws + OFFB_PFX);
  int*          kkb  = (int*)(ws + OFFB_KK);
  float*  x2    = outp;

  auto run_select = [&](const float* data, int count, int k, int split,
                        float* out) {
    rsel_init_kernel<<<NSEG_, 256, 0, stream>>>(hist, pfx, kkb, k);
    for (int shift = 24; shift >= 0; shift -= 8) {
      rsel_hist_kernel<<<NSEG_ * split, 256, 0, stream>>>(
          data, count, split, pfx, hist, shift);
      rsel_scan_kernel<<<3, 256, 0, stream>>>(
          hist, pfx, kkb, shift, (shift == 0) ? out : nullptr);
    }
  };

  // Weight conversions needed early
  wsplit_kernel<<<(2304 * 768 + 255) / 256, 256, 0, stream>>>(
      qkvw, qwhi, qwlo, 2304 * 768);
  wconv_kernel<<<(768 * 768 + 255) / 256, 256, 0, stream>>>(
      projw, prjwb, 768 * 768);
  // 1. LN1 -> split bf16 (pad rows zeroed)
  ln_bf16_kernel<<<M1P_, 256, 0, stream>>>(x, n1w, n1b, xa_hi, xa_lo, M1_);
  // 2a. q,k = split GEMM (N=1536) -> hi/lo bf16
  gemm_split_kernel<<<dim3(1536 / 128, M1P_ / 128), 256, 0, stream>>>(
      xa_hi, xa_lo, qwhi, qwlo, qhi, qlo, 1536, C_);
  // 2b. v = plain bf16 GEMM (N=768) -> bf16
  gemm_bf16_kernel<<<dim3(C_ / 128, M1P_ / 128), 256, 0, stream>>>(
      xa_hi, qwhi + (size_t)1536 * C_, nullptr, nullptr, nullptr, vb,
      M1P_, C_, C_, 0);
  // 3. scores via split MFMA (attn overwrites xa region; xa dead)
  scores_mfma_kernel<<<B_ * H_, 256, 0, stream>>>(qhi, qlo, attn);
  // 4. softmax
  softmax_kernel<<<(B_ * H_ * N_) / 4, 256, 0, stream>>>(attn);
  // 5. sigma per (b,h) — parallel radix select (split=16)
  run_select(attn, N_ * N_, KASC_ATTN, 16, sig);
  // 6. attn @ v via MFMA (threshold folded into staging) -> aout bf16
  attn_v_mfma_kernel<<<dim3(B_ * H_, 4), 256, 0, stream>>>(attn, sig, vb, aout);
  // 7. token_rank (thresholded diag) + stable order
  token_rank_kernel<<<B_, 256, 0, stream>>>(attn, sig, tr);
  order_kernel<<<B_, 256, 0, stream>>>(tr, ord);
  // 8. x1 = x + aout @ proj_w.T + proj_b (fp32)
  gemm_bf16_kernel<<<dim3(C_ / 128, M1P_ / 128), 256, 0, stream>>>(
      aout, prjwb, projb, x, x1, nullptr, M1_, C_, C_, 0);
  // 9. w gather (threshold folded) + w_sigma + w threshold
  {
    const int total = B_ * H_ * NK_ * NP_;
    w_gather_kernel<<<(total + 255) / 256, 256, 0, stream>>>(attn, sig, ord, wbuf);
    run_select(wbuf, NK_ * NP_, KASC_W, 4, wsig);
    threshold_kernel<<<(total + 255) / 256, 256, 0, stream>>>(wbuf, wsig, total,
                                                              NK_ * NP_);
  }
  // attn now dead -> convert fc1/fc2 weights into tail of region A
  wconv_kernel<<<(MLP_ * C_ + 255) / 256, 256, 0, stream>>>(
      fc1w, fc1wb, MLP_ * C_);
  wconv_kernel<<<(C_ * MLP_ + 255) / 256, 256, 0, stream>>>(
      fc2w, fc2wb, C_ * MLP_);
  // 10. x_prop + assemble x2 (d_out)
  xprop_kernel<<<dim3(N2_, B_), 256, 0, stream>>>(x1, wbuf, ord, x2);
  // 11. LN2 -> bf16 (pad rows zeroed)
  ln_bf16_kernel<<<M2P_, 256, 0, stream>>>(x2, n2w, n2b, h2, nullptr, M2_);
  // 12. fc1 + bias + gelu -> bf16
  gemm_bf16_kernel<<<dim3(MLP_ / 128, M2P_ / 128), 256, 0, stream>>>(
      h2, fc1wb, fc1b, nullptr, nullptr, fc1h, M2P_, MLP_, C_, 1);
  // 13. out = x2 + fc1h @ fc2_w.T + fc2_b (in-place on d_out)
  gemm_bf16_kernel<<<dim3(C_ / 128, M2P_ / 128), 256, 0, stream>>>(
      fc1h, fc2wb, fc2b, x2, outp, nullptr, M2_, C_, MLP_, 0);
}

// Round 8
// 1157.849 us; speedup vs baseline: 2.0170x; 1.6676x over previous
//
#include <hip/hip_runtime.h>
#include <math.h>

// ---------------------------------------------------------------------------
// Problem constants
// ---------------------------------------------------------------------------
constexpr int B_  = 64;
constexpr int N_  = 197;
constexpr int C_  = 768;
constexpr int H_  = 12;
constexpr int HD_ = 64;
constexpr int NP_ = 40;
constexpr int NK_ = 156;
constexpr int N1_ = 196;
constexpr int N2_ = 157;
constexpr int MLP_ = 3072;
constexpr int M1_ = B_ * N_;    // 12608
constexpr int M2_ = B_ * N2_;   // 10048
constexpr int M1P_ = 12672;     // pad to 128
constexpr int M2P_ = 10112;     // pad to 128
constexpr float SCALE_ = 0.125f;
constexpr float ALPHA_ = 0.1f;
constexpr float EPS_   = 1e-5f;
constexpr int KASC_ATTN = N_ * N_ - 1 - 29106;   // 9702
constexpr int KASC_W    = NK_ * NP_ - 1 - 312;   // 5927
constexpr int NSEG_ = B_ * H_;  // 768

typedef __bf16 bf16x8 __attribute__((ext_vector_type(8)));
typedef float  floatx4 __attribute__((ext_vector_type(4)));

// ---------------------------------------------------------------------------
// Workspace layout (byte offsets) — same envelope as rounds 3-6 (~215.3 MiB,
// proven to fit).
// ---------------------------------------------------------------------------
constexpr size_t A_B     = 0;
constexpr size_t OFFB_XAHI = A_B;                        // bf16 M1P*C
constexpr size_t OFFB_XALO = A_B + 19464192;             // bf16 M1P*C
constexpr size_t OFFB_ATTN = A_B;                        // fp32 768*197*197
constexpr size_t OFFB_FC1H = A_B;                        // bf16 M2P*3072
constexpr size_t OFFB_H2   = A_B + 62128128;             // bf16 M2P*768
constexpr size_t OFFB_FC1W = A_B + 77660160;             // bf16 3072*768
constexpr size_t OFFB_FC2W = A_B + 82378752;             // bf16 768*3072
constexpr size_t B_B     = 119221248;
constexpr size_t OFFB_QHI  = B_B;                        // bf16 M1P*1536
constexpr size_t OFFB_QLO  = B_B + 38928384;             // bf16 M1P*1536
constexpr size_t OFFB_VB   = B_B + 77856768;             // bf16 M1P*768
constexpr size_t OFFB_X1   = B_B;                        // fp32 M1P*768
constexpr size_t OFFB_AOUT = B_B + 38928384;             // bf16 M1P*768
constexpr size_t OFFB_WBUF = B_B + 77856768;             // fp32 768*156*40
constexpr size_t W_B     = 216542208;
constexpr size_t OFFB_QWHI = W_B;                        // bf16 2304*768
constexpr size_t OFFB_QWLO = W_B + 3538944;
constexpr size_t OFFB_PRJW = W_B + 7077888;              // bf16 768*768
constexpr size_t S_B     = 224799744;
constexpr size_t OFFB_SIG  = S_B;                        // 3072
constexpr size_t OFFB_WSIG = S_B + 3072;                 // 3072
constexpr size_t OFFB_TR   = S_B + 6144;                 // 50176
constexpr size_t OFFB_ORD  = S_B + 56320;                // 50176
constexpr size_t OFFB_HIST = S_B + 106496;               // u32 768*256 = 786432
constexpr size_t OFFB_PFX  = S_B + 892928;               // u32 768
constexpr size_t OFFB_KK   = S_B + 896000;               // i32 768

// ---------------------------------------------------------------------------
// Weight conversion kernels
// ---------------------------------------------------------------------------
__global__ __launch_bounds__(256) void wsplit_kernel(
    const float* __restrict__ w, __bf16* __restrict__ hi,
    __bf16* __restrict__ lo, int n)
{
  const int i = blockIdx.x * 256 + threadIdx.x;
  if (i >= n) return;
  const float v = w[i];
  const __bf16 h = (__bf16)v;
  hi[i] = h;
  lo[i] = (__bf16)(v - (float)h);
}

__global__ __launch_bounds__(256) void wconv_kernel(
    const float* __restrict__ w, __bf16* __restrict__ o, int n)
{
  const int i = blockIdx.x * 256 + threadIdx.x;
  if (i < n) o[i] = (__bf16)w[i];
}

// ---------------------------------------------------------------------------
// Helpers
// ---------------------------------------------------------------------------
__device__ __forceinline__ float block_reduce_sum(float v, float* red) {
  #pragma unroll
  for (int off = 32; off; off >>= 1) v += __shfl_xor(v, off);
  if ((threadIdx.x & 63) == 0) red[threadIdx.x >> 6] = v;
  __syncthreads();
  float r = red[0] + red[1] + red[2] + red[3];
  __syncthreads();
  return r;
}

// ---------------------------------------------------------------------------
// LayerNorm -> bf16 (optionally split hi/lo). Pad rows (>= Mvalid) -> zeros.
// ---------------------------------------------------------------------------
__global__ __launch_bounds__(256) void ln_bf16_kernel(
    const float* __restrict__ x, const float* __restrict__ w,
    const float* __restrict__ b, __bf16* __restrict__ ohi,
    __bf16* __restrict__ olo, int Mvalid)
{
  __shared__ float red[4];
  const size_t row = blockIdx.x;
  const int t = threadIdx.x;
  if ((int)row >= Mvalid) {
    #pragma unroll
    for (int i = 0; i < 3; ++i) {
      ohi[row * C_ + t + 256 * i] = (__bf16)0.f;
      if (olo) olo[row * C_ + t + 256 * i] = (__bf16)0.f;
    }
    return;
  }
  const float* xr = x + row * C_;
  float v[3];
  float s = 0.f;
  #pragma unroll
  for (int i = 0; i < 3; ++i) { v[i] = xr[t + 256 * i]; s += v[i]; }
  const float mu = block_reduce_sum(s, red) * (1.f / 768.f);
  s = 0.f;
  #pragma unroll
  for (int i = 0; i < 3; ++i) { float d = v[i] - mu; s += d * d; }
  const float var = block_reduce_sum(s, red) * (1.f / 768.f);
  const float rs = rsqrtf(var + EPS_);
  #pragma unroll
  for (int i = 0; i < 3; ++i) {
    const int c = t + 256 * i;
    const float val = (v[i] - mu) * rs * w[c] + b[c];
    const __bf16 h = (__bf16)val;
    ohi[row * C_ + c] = h;
    if (olo) olo[row * C_ + c] = (__bf16)(val - (float)h);
  }
}

// ---------------------------------------------------------------------------
// MFMA tile staging: 128x32 bf16 tile, global -> LDS via global_load_lds x16B
// ---------------------------------------------------------------------------
__device__ __forceinline__ void stage_tile(
    const __bf16* __restrict__ gbase, int ldg, __bf16* lds, int wave, int lane)
{
  #pragma unroll
  for (int j = 0; j < 2; ++j) {
    const int seg = 4 * j + wave;
    const int row = seg * 16 + (lane >> 2);
    const int col = (lane & 3) * 8;
    const __bf16* g = gbase + (size_t)row * ldg + col;
    __bf16* l = lds + seg * 512 + lane * 8;
    __builtin_amdgcn_global_load_lds(
        (const __attribute__((address_space(1))) unsigned int*)g,
        (__attribute__((address_space(3))) unsigned int*)l, 16, 0, 0);
  }
}

__device__ __forceinline__ bf16x8 frag(const __bf16* lds, int r, int hi8) {
  return *(const bf16x8*)(lds + r * 32 + hi8);
}

// ---------------------------------------------------------------------------
// Plain bf16 MFMA GEMM: C[m,n] = sum_k A[m,k]*Bw[n,k] (+bias,+gelu,+res)
// ---------------------------------------------------------------------------
__global__ __launch_bounds__(256) void gemm_bf16_kernel(
    const __bf16* __restrict__ A, const __bf16* __restrict__ Bw,
    const float* __restrict__ bias, const float* __restrict__ res,
    float* __restrict__ outf, __bf16* __restrict__ outb,
    int Mstore, int Nn, int K, int act)
{
  __shared__ __bf16 As[128 * 32];
  __shared__ __bf16 Bs[128 * 32];
  const int t = threadIdx.x;
  const int wave = t >> 6, lane = t & 63;
  const int m0 = blockIdx.y * 128, n0 = blockIdx.x * 128;
  const int wm = (wave >> 1) * 64, wn = (wave & 1) * 64;
  const int lo = lane & 15, hi8 = (lane >> 4) * 8;
  floatx4 acc[4][4] = {};
  for (int k0 = 0; k0 < K; k0 += 32) {
    stage_tile(A + (size_t)m0 * K + k0, K, As, wave, lane);
    stage_tile(Bw + (size_t)n0 * K + k0, K, Bs, wave, lane);
    __syncthreads();
    bf16x8 af[4], bfr[4];
    #pragma unroll
    for (int i = 0; i < 4; ++i) af[i]  = frag(As, wm + i * 16 + lo, hi8);
    #pragma unroll
    for (int j = 0; j < 4; ++j) bfr[j] = frag(Bs, wn + j * 16 + lo, hi8);
    #pragma unroll
    for (int i = 0; i < 4; ++i)
      #pragma unroll
      for (int j = 0; j < 4; ++j)
        acc[i][j] = __builtin_amdgcn_mfma_f32_16x16x32_bf16(
            af[i], bfr[j], acc[i][j], 0, 0, 0);
    __syncthreads();
  }
  #pragma unroll
  for (int i = 0; i < 4; ++i) {
    #pragma unroll
    for (int j = 0; j < 4; ++j) {
      #pragma unroll
      for (int r = 0; r < 4; ++r) {
        const int m = m0 + wm + i * 16 + (lane >> 4) * 4 + r;
        const int n = n0 + wn + j * 16 + lo;
        if (m < Mstore) {
          float v = acc[i][j][r];
          if (bias) v += bias[n];
          if (act) v = 0.5f * v * (1.0f + erff(v * 0.7071067811865476f));
          if (res) v += res[(size_t)m * Nn + n];
          if (outf) outf[(size_t)m * Nn + n] = v;
          else      outb[(size_t)m * Nn + n] = (__bf16)v;
        }
      }
    }
  }
}

// ---------------------------------------------------------------------------
// Split-bf16 MFMA GEMM: acc = Ah*Bh + Ah*Bl + Al*Bh; output split hi/lo bf16.
// ---------------------------------------------------------------------------
__global__ __launch_bounds__(256) void gemm_split_kernel(
    const __bf16* __restrict__ Ah, const __bf16* __restrict__ Al,
    const __bf16* __restrict__ Bh, const __bf16* __restrict__ Bl,
    __bf16* __restrict__ outhi, __bf16* __restrict__ outlo, int Nn, int K)
{
  __shared__ __bf16 Ahs[128 * 32];
  __shared__ __bf16 Als[128 * 32];
  __shared__ __bf16 Bhs[128 * 32];
  __shared__ __bf16 Bls[128 * 32];
  const int t = threadIdx.x;
  const int wave = t >> 6, lane = t & 63;
  const int m0 = blockIdx.y * 128, n0 = blockIdx.x * 128;
  const int wm = (wave >> 1) * 64, wn = (wave & 1) * 64;
  const int lo = lane & 15, hi8 = (lane >> 4) * 8;
  floatx4 acc[4][4] = {};
  for (int k0 = 0; k0 < K; k0 += 32) {
    stage_tile(Ah + (size_t)m0 * K + k0, K, Ahs, wave, lane);
    stage_tile(Al + (size_t)m0 * K + k0, K, Als, wave, lane);
    stage_tile(Bh + (size_t)n0 * K + k0, K, Bhs, wave, lane);
    stage_tile(Bl + (size_t)n0 * K + k0, K, Bls, wave, lane);
    __syncthreads();
    bf16x8 ah[4], al[4], bh[4], bl[4];
    #pragma unroll
    for (int i = 0; i < 4; ++i) {
      ah[i] = frag(Ahs, wm + i * 16 + lo, hi8);
      al[i] = frag(Als, wm + i * 16 + lo, hi8);
    }
    #pragma unroll
    for (int j = 0; j < 4; ++j) {
      bh[j] = frag(Bhs, wn + j * 16 + lo, hi8);
      bl[j] = frag(Bls, wn + j * 16 + lo, hi8);
    }
    #pragma unroll
    for (int i = 0; i < 4; ++i)
      #pragma unroll
      for (int j = 0; j < 4; ++j) {
        acc[i][j] = __builtin_amdgcn_mfma_f32_16x16x32_bf16(
            ah[i], bh[j], acc[i][j], 0, 0, 0);
        acc[i][j] = __builtin_amdgcn_mfma_f32_16x16x32_bf16(
            ah[i], bl[j], acc[i][j], 0, 0, 0);
        acc[i][j] = __builtin_amdgcn_mfma_f32_16x16x32_bf16(
            al[i], bh[j], acc[i][j], 0, 0, 0);
      }
    __syncthreads();
  }
  #pragma unroll
  for (int i = 0; i < 4; ++i)
    #pragma unroll
    for (int j = 0; j < 4; ++j)
      #pragma unroll
      for (int r = 0; r < 4; ++r) {
        const int m = m0 + wm + i * 16 + (lane >> 4) * 4 + r;
        const int n = n0 + wn + j * 16 + lo;
        const float v = acc[i][j][r];
        const __bf16 h = (__bf16)v;
        outhi[(size_t)m * Nn + n] = h;
        outlo[(size_t)m * Nn + n] = (__bf16)(v - (float)h);
      }
}

// ---------------------------------------------------------------------------
// Scores via split-bf16 MFMA: per (b,h), S = scale * (Qhi+Qlo)(Khi+Klo)^T.
// ---------------------------------------------------------------------------
__global__ __launch_bounds__(256) void scores_mfma_kernel(
    const __bf16* __restrict__ qhi, const __bf16* __restrict__ qlo,
    float* __restrict__ attn)
{
  const int bh = blockIdx.x;
  const int b = bh / H_, h = bh % H_;
  __shared__ __bf16 Khi[208 * 72];
  __shared__ __bf16 Klo[208 * 72];
  const int t = threadIdx.x;
  for (int idx = t; idx < 208 * 32; idx += 256) {
    const int j = idx >> 5;
    const int c2 = (idx & 31) * 2;
    unsigned int vh = 0u, vl = 0u;
    if (j < N_) {
      const size_t g = ((size_t)(b * N_ + j)) * 1536 + 768 + h * HD_ + c2;
      vh = *(const unsigned int*)(qhi + g);
      vl = *(const unsigned int*)(qlo + g);
    }
    *(unsigned int*)(Khi + j * 72 + c2) = vh;
    *(unsigned int*)(Klo + j * 72 + c2) = vl;
  }
  __syncthreads();
  const int wave = t >> 6, lane = t & 63;
  const int lo16 = lane & 15, k8 = (lane >> 4) * 8;
  float* Sbh = attn + (size_t)bh * N_ * N_;
  bf16x8 zf;
  #pragma unroll
  for (int e = 0; e < 8; ++e) zf[e] = (__bf16)0.f;
  for (int i = 0; i < 4; ++i) {
    const int mrow = wave * 64 + i * 16 + lo16;
    bf16x8 ahi[2], alo[2];
    #pragma unroll
    for (int kk = 0; kk < 2; ++kk) {
      if (mrow < N_) {
        const size_t g = ((size_t)(b * N_ + mrow)) * 1536 + h * HD_ + kk * 32 + k8;
        ahi[kk] = *(const bf16x8*)(qhi + g);
        alo[kk] = *(const bf16x8*)(qlo + g);
      } else {
        ahi[kk] = zf;
        alo[kk] = zf;
      }
    }
    for (int j = 0; j < 13; ++j) {
      floatx4 acc = {0.f, 0.f, 0.f, 0.f};
      #pragma unroll
      for (int kk = 0; kk < 2; ++kk) {
        const bf16x8 bh_ = *(const bf16x8*)(Khi + (j * 16 + lo16) * 72 + kk * 32 + k8);
        const bf16x8 bl_ = *(const bf16x8*)(Klo + (j * 16 + lo16) * 72 + kk * 32 + k8);
        acc = __builtin_amdgcn_mfma_f32_16x16x32_bf16(ahi[kk], bh_, acc, 0, 0, 0);
        acc = __builtin_amdgcn_mfma_f32_16x16x32_bf16(ahi[kk], bl_, acc, 0, 0, 0);
        acc = __builtin_amdgcn_mfma_f32_16x16x32_bf16(alo[kk], bh_, acc, 0, 0, 0);
        acc = __builtin_amdgcn_mfma_f32_16x16x32_bf16(alo[kk], bl_, acc, 0, 0, 0);
      }
      const int col = j * 16 + lo16;
      if (col < N_) {
        #pragma unroll
        for (int r = 0; r < 4; ++r) {
          const int row = wave * 64 + i * 16 + (lane >> 4) * 4 + r;
          if (row < N_) Sbh[(size_t)row * N_ + col] = acc[r] * SCALE_;
        }
      }
    }
  }
}

// ---------------------------------------------------------------------------
// Softmax along last dim (197). One wave per row, 4 rows per block.
// ---------------------------------------------------------------------------
__global__ __launch_bounds__(256) void softmax_kernel(float* __restrict__ attn)
{
  const int row = blockIdx.x * 4 + (threadIdx.x >> 6);
  const int lane = threadIdx.x & 63;
  float* r = attn + (size_t)row * N_;
  float vals[4];
  float m = -1e30f;
  int cnt = 0;
  for (int j = lane; j < N_; j += 64) { vals[cnt] = r[j]; m = fmaxf(m, vals[cnt]); ++cnt; }
  #pragma unroll
  for (int off = 32; off; off >>= 1) m = fmaxf(m, __shfl_xor(m, off));
  float s = 0.f;
  for (int i = 0; i < cnt; ++i) { vals[i] = expf(vals[i] - m); s += vals[i]; }
  #pragma unroll
  for (int off = 32; off; off >>= 1) s += __shfl_xor(s, off);
  const float inv = 1.0f / s;
  cnt = 0;
  for (int j = lane; j < N_; j += 64) { r[j] = vals[cnt] * inv; ++cnt; }
}

// ---------------------------------------------------------------------------
// Parallel exact radix select. Hybrid histogram increment: the wave's
// majority bin is counted with ONE ballot+popcount+atomic (clustered case,
// e.g. pass 1 over softmax exponents); minority lanes use per-lane atomics
// (uniform case, conflicts rare). Fixes both round-5 (ballot loop on uniform
// data: 64x VALU) and round-6 (per-lane atomics on clustered data: 64x
// serialization) failure modes.
// ---------------------------------------------------------------------------
__global__ __launch_bounds__(256) void rsel_init_kernel(
    unsigned int* __restrict__ hist, unsigned int* __restrict__ prefix,
    int* __restrict__ kk, int k)
{
  const int i = blockIdx.x * 256 + threadIdx.x;
  hist[i] = 0u;                       // grid covers NSEG_*256 exactly
  if (i < NSEG_) { prefix[i] = 0u; kk[i] = k; }
}

__device__ __forceinline__ void hist_inc(
    unsigned int* lh, int bin, bool active)
{
  const unsigned long long act = __ballot(active);
  if (!act) return;
  const int lane = threadIdx.x & 63;
  const int leader = __ffsll(act) - 1;
  const int lead_bin = __shfl(bin, leader);
  const unsigned long long same = __ballot(active && (bin == lead_bin));
  if (active) {
    if (bin == lead_bin) {
      if (lane == leader)
        atomicAdd(&lh[bin], (unsigned int)__popcll(same));
    } else {
      atomicAdd(&lh[bin], 1u);
    }
  }
}

__global__ __launch_bounds__(256) void rsel_hist_kernel(
    const float* __restrict__ data, int count, int split,
    const unsigned int* __restrict__ prefix, unsigned int* __restrict__ hist,
    int shift)
{
  const int seg = blockIdx.x / split;
  const int sub = blockIdx.x % split;
  const float* sd = data + (size_t)seg * count;
  __shared__ unsigned int lh[256];
  lh[threadIdx.x] = 0u;
  __syncthreads();
  const unsigned int pfx = prefix[seg];
  const unsigned int mask_known =
      (shift == 24) ? 0u : (0xFFFFFFFFu << (shift + 8));
  const int step = split * 256;
  // Uniform trip count per wave; boundary via predicate (keeps ballot legal).
  for (int i0 = sub * 256; i0 < count; i0 += step) {
    const int i = i0 + (int)threadIdx.x;
    const bool inb = i < count;
    const unsigned int bits = inb ? __float_as_uint(sd[i]) : 0u;
    const bool act = inb && ((bits & mask_known) == pfx);
    hist_inc(lh, (int)((bits >> shift) & 0xFFu), act);
  }
  __syncthreads();
  const unsigned int c = lh[threadIdx.x];
  if (c) atomicAdd(&hist[seg * 256 + threadIdx.x], c);
}

// Wave-per-segment scan: 4 bins/lane, wave prefix-sum, pick digit, zero hist.
__global__ __launch_bounds__(256) void rsel_scan_kernel(
    unsigned int* __restrict__ hist, unsigned int* __restrict__ prefix,
    int* __restrict__ kk, int shift, float* __restrict__ out)
{
  const int wave = threadIdx.x >> 6;
  const int lane = threadIdx.x & 63;
  const int seg = blockIdx.x * 4 + wave;   // grid 192 -> 768 segs exact
  unsigned int* h = hist + (size_t)seg * 256 + lane * 4;
  const unsigned int c0 = h[0], c1 = h[1], c2 = h[2], c3 = h[3];
  h[0] = 0u; h[1] = 0u; h[2] = 0u; h[3] = 0u;   // zero for next pass
  const unsigned int lsum = c0 + c1 + c2 + c3;
  unsigned int p = lsum;
  #pragma unroll
  for (int off = 1; off < 64; off <<= 1) {
    const unsigned int tv = __shfl_up(p, off);
    if (lane >= off) p += tv;
  }
  const unsigned int excl = p - lsum;
  const unsigned int rem = (unsigned int)kk[seg];
  if (excl <= rem && rem < excl + lsum) {
    unsigned int r = rem - excl;
    unsigned int d;
    if (r < c0)                { d = lane * 4 + 0; }
    else if (r < c0 + c1)      { d = lane * 4 + 1; r -= c0; }
    else if (r < c0 + c1 + c2) { d = lane * 4 + 2; r -= c0 + c1; }
    else                       { d = lane * 4 + 3; r -= c0 + c1 + c2; }
    const unsigned int np = prefix[seg] | (d << shift);
    prefix[seg] = np;
    kk[seg] = (int)r;
    if (shift == 0 && out) out[seg] = __uint_as_float(np);
  }
}

__global__ __launch_bounds__(256) void threshold_kernel(
    float* __restrict__ a, const float* __restrict__ sig, int total, int seglen)
{
  const int idx = blockIdx.x * 256 + threadIdx.x;
  if (idx >= total) return;
  const float v = a[idx];
  if (v < sig[idx / seglen]) a[idx] = 0.0f;
}

// ---------------------------------------------------------------------------
// attn @ v via bf16 MFMA. One block per (b,h): V^T staged ONCE with
// coalesced row-major global reads (4B) + LDS transpose writes, then loop
// over 4 m-tiles staging thresholded P. Threshold folded into P staging.
// ---------------------------------------------------------------------------
__global__ __launch_bounds__(256) void attn_v_mfma_kernel(
    const float* __restrict__ attn, const float* __restrict__ sig,
    const __bf16* __restrict__ v, __bf16* __restrict__ out)
{
  const int bh = blockIdx.x;
  const int b = bh / H_, h = bh % H_;
  __shared__ __bf16 Ps[64 * 232];
  __shared__ __bf16 Vt[64 * 232];
  unsigned short* Vt_u = (unsigned short*)Vt;
  const int t = threadIdx.x;
  const float sigbh = sig[bh];
  const float* abase = attn + (size_t)bh * N_ * N_;
  // stage V^T: coalesced 4B reads of v rows, transpose into Vt[d][j]
  for (int idx = t; idx < N_ * 32; idx += 256) {
    const int j = idx >> 5;
    const int d2 = (idx & 31) * 2;
    const unsigned int pair =
        *(const unsigned int*)(v + ((size_t)(b * N_ + j)) * C_ + h * HD_ + d2);
    Vt_u[d2 * 232 + j]       = (unsigned short)(pair & 0xFFFFu);
    Vt_u[(d2 + 1) * 232 + j] = (unsigned short)(pair >> 16);
  }
  // zero pad columns j in [197, 224)
  for (int idx = t; idx < 64 * 27; idx += 256) {
    const int d = idx / 27;
    const int j = N_ + idx % 27;
    Vt[d * 232 + j] = (__bf16)0.f;
  }
  const int wave = t >> 6, lane = t & 63;
  const int lo16 = lane & 15, k8 = (lane >> 4) * 8;
  for (int mt = 0; mt < 4; ++mt) {
    __syncthreads();   // Vt ready (first iter) / prior MFMA reads done
    // stage P (thresholded, bf16), zero pads. dword-pair granularity.
    for (int idx = t; idx < 64 * 112; idx += 256) {
      const int r = idx / 112;
      const int j0 = (idx % 112) * 2;
      const int gr = mt * 64 + r;
      float v0 = 0.f, v1 = 0.f;
      if (gr < N_) {
        if (j0 < N_)     { const float a0 = abase[(size_t)gr * N_ + j0];     v0 = (a0 >= sigbh) ? a0 : 0.f; }
        if (j0 + 1 < N_) { const float a1 = abase[(size_t)gr * N_ + j0 + 1]; v1 = (a1 >= sigbh) ? a1 : 0.f; }
      }
      __bf16 p2[2] = {(__bf16)v0, (__bf16)v1};
      *(unsigned int*)(Ps + r * 232 + j0) = *(unsigned int*)p2;
    }
    __syncthreads();
    #pragma unroll
    for (int jn = 0; jn < 4; ++jn) {
      floatx4 acc = {0.f, 0.f, 0.f, 0.f};
      #pragma unroll
      for (int kk = 0; kk < 7; ++kk) {
        const bf16x8 a = *(const bf16x8*)(Ps + (wave * 16 + lo16) * 232 + kk * 32 + k8);
        const bf16x8 bb = *(const bf16x8*)(Vt + (jn * 16 + lo16) * 232 + kk * 32 + k8);
        acc = __builtin_amdgcn_mfma_f32_16x16x32_bf16(a, bb, acc, 0, 0, 0);
      }
      const int d = jn * 16 + lo16;
      #pragma unroll
      for (int r = 0; r < 4; ++r) {
        const int m = mt * 64 + wave * 16 + (lane >> 4) * 4 + r;
        if (m < N_)
          out[((size_t)b * N_ + m) * C_ + h * HD_ + d] = (__bf16)acc[r];
      }
    }
  }
}

// ---------------------------------------------------------------------------
// token_rank / order / w gather / xprop
// ---------------------------------------------------------------------------
__global__ __launch_bounds__(256) void token_rank_kernel(
    const float* __restrict__ attn, const float* __restrict__ sig,
    float* __restrict__ tr)
{
  const int b = blockIdx.x;
  for (int j = threadIdx.x; j < N1_; j += 256) {
    const int n = j + 1;
    float s = 0.f;
    #pragma unroll
    for (int h = 0; h < H_; ++h) {
      const float d = attn[(((size_t)(b * H_ + h)) * N_ + n) * N_ + n];
      s += (d >= sig[b * H_ + h]) ? d : 0.f;
    }
    tr[b * N1_ + j] = s * (1.f / H_);
  }
}

__global__ __launch_bounds__(256) void order_kernel(
    const float* __restrict__ tr, int* __restrict__ order)
{
  const int b = blockIdx.x;
  __shared__ float v[N1_];
  const int t = threadIdx.x;
  if (t < N1_) v[t] = tr[b * N1_ + t];
  __syncthreads();
  if (t < N1_) {
    const float mv = v[t];
    int r = 0;
    for (int i = 0; i < N1_; ++i) {
      const float vi = v[i];
      r += (vi > mv) || (vi == mv && i < t);
    }
    order[b * N1_ + r] = t;
  }
}

__global__ __launch_bounds__(256) void w_gather_kernel(
    const float* __restrict__ attn, const float* __restrict__ sig,
    const int* __restrict__ ord, float* __restrict__ w)
{
  const int idx = blockIdx.x * 256 + threadIdx.x;
  if (idx >= B_ * H_ * NK_ * NP_) return;
  const int e = idx % NP_;
  const int k = (idx / NP_) % NK_;
  const int h = (idx / (NP_ * NK_)) % H_;
  const int b = idx / (NP_ * NK_ * H_);
  const int ki = ord[b * N1_ + k] + 1;
  const int ej = ord[b * N1_ + NK_ + e] + 1;
  const float v = attn[(((size_t)b * H_ + h) * N_ + ki) * N_ + ej];
  w[idx] = (v >= sig[b * H_ + h]) ? v : 0.f;
}

__global__ __launch_bounds__(256) void xprop_kernel(
    const float* __restrict__ x1, const float* __restrict__ w,
    const int* __restrict__ ord, float* __restrict__ x2)
{
  const int b = blockIdx.y;
  const int kk = blockIdx.x;
  const int t = threadIdx.x;
  if (kk == 0) {
    for (int c = t; c < C_; c += 256)
      x2[(size_t)b * N2_ * C_ + c] = x1[(size_t)b * N_ * C_ + c];
    return;
  }
  const int k = kk - 1;
  __shared__ float ws_[H_ * NP_];
  __shared__ int es[NP_];
  if (t < NP_) es[t] = ord[b * N1_ + NK_ + t] + 1;
  for (int i = t; i < H_ * NP_; i += 256) {
    const int h = i / NP_, e = i % NP_;
    ws_[i] = w[(((size_t)b * H_ + h) * NK_ + k) * NP_ + e];
  }
  __syncthreads();
  const int kept = ord[b * N1_ + k] + 1;
  const float* xk = x1 + ((size_t)b * N_ + kept) * C_;
  float* xo = x2 + ((size_t)b * N2_ + 1 + k) * C_;
  for (int c = t; c < C_; c += 256) {
    const int h = c >> 6;
    float acc = 0.f;
    #pragma unroll 8
    for (int e = 0; e < NP_; ++e)
      acc += ws_[h * NP_ + e] * x1[((size_t)b * N_ + es[e]) * C_ + c];
    xo[c] = xk[c] + ALPHA_ * acc;
  }
}

// ---------------------------------------------------------------------------
// Launcher
// ---------------------------------------------------------------------------
extern "C" void kernel_launch(void* const* d_in, const int* in_sizes, int n_in,
                              void* d_out, int out_size, void* d_ws, size_t ws_size,
                              hipStream_t stream)
{
  const float* x     = (const float*)d_in[0];
  const float* n1w   = (const float*)d_in[1];
  const float* n1b   = (const float*)d_in[2];
  const float* qkvw  = (const float*)d_in[3];
  const float* projw = (const float*)d_in[4];
  const float* projb = (const float*)d_in[5];
  const float* n2w   = (const float*)d_in[6];
  const float* n2b   = (const float*)d_in[7];
  const float* fc1w  = (const float*)d_in[8];
  const float* fc1b  = (const float*)d_in[9];
  const float* fc2w  = (const float*)d_in[10];
  const float* fc2b  = (const float*)d_in[11];
  float* outp = (float*)d_out;

  char* ws = (char*)d_ws;
  __bf16* xa_hi = (__bf16*)(ws + OFFB_XAHI);
  __bf16* xa_lo = (__bf16*)(ws + OFFB_XALO);
  float*  attn  = (float*)(ws + OFFB_ATTN);
  __bf16* fc1h  = (__bf16*)(ws + OFFB_FC1H);
  __bf16* h2    = (__bf16*)(ws + OFFB_H2);
  __bf16* fc1wb = (__bf16*)(ws + OFFB_FC1W);
  __bf16* fc2wb = (__bf16*)(ws + OFFB_FC2W);
  __bf16* qhi   = (__bf16*)(ws + OFFB_QHI);
  __bf16* qlo   = (__bf16*)(ws + OFFB_QLO);
  __bf16* vb    = (__bf16*)(ws + OFFB_VB);
  float*  x1    = (float*)(ws + OFFB_X1);
  __bf16* aout  = (__bf16*)(ws + OFFB_AOUT);
  float*  wbuf  = (float*)(ws + OFFB_WBUF);
  __bf16* qwhi  = (__bf16*)(ws + OFFB_QWHI);
  __bf16* qwlo  = (__bf16*)(ws + OFFB_QWLO);
  __bf16* prjwb = (__bf16*)(ws + OFFB_PRJW);
  float*  sig   = (float*)(ws + OFFB_SIG);
  float*  wsig  = (float*)(ws + OFFB_WSIG);
  float*  tr    = (float*)(ws + OFFB_TR);
  int*    ord   = (int*)(ws + OFFB_ORD);
  unsigned int* hist = (unsigned int*)(ws + OFFB_HIST);
  unsigned int* pfx  = (unsigned int*)(ws + OFFB_PFX);
  int*          kkb  = (int*)(ws + OFFB_KK);
  float*  x2    = outp;

  auto run_select = [&](const float* data, int count, int k, int split,
                        float* out) {
    rsel_init_kernel<<<NSEG_, 256, 0, stream>>>(hist, pfx, kkb, k);
    for (int shift = 24; shift >= 0; shift -= 8) {
      rsel_hist_kernel<<<NSEG_ * split, 256, 0, stream>>>(
          data, count, split, pfx, hist, shift);
      rsel_scan_kernel<<<NSEG_ / 4, 256, 0, stream>>>(
          hist, pfx, kkb, shift, (shift == 0) ? out : nullptr);
    }
  };

  // Weight conversions needed early
  wsplit_kernel<<<(2304 * 768 + 255) / 256, 256, 0, stream>>>(
      qkvw, qwhi, qwlo, 2304 * 768);
  wconv_kernel<<<(768 * 768 + 255) / 256, 256, 0, stream>>>(
      projw, prjwb, 768 * 768);
  // 1. LN1 -> split bf16 (pad rows zeroed)
  ln_bf16_kernel<<<M1P_, 256, 0, stream>>>(x, n1w, n1b, xa_hi, xa_lo, M1_);
  // 2a. q,k = split GEMM (N=1536) -> hi/lo bf16
  gemm_split_kernel<<<dim3(1536 / 128, M1P_ / 128), 256, 0, stream>>>(
      xa_hi, xa_lo, qwhi, qwlo, qhi, qlo, 1536, C_);
  // 2b. v = plain bf16 GEMM (N=768) -> bf16
  gemm_bf16_kernel<<<dim3(C_ / 128, M1P_ / 128), 256, 0, stream>>>(
      xa_hi, qwhi + (size_t)1536 * C_, nullptr, nullptr, nullptr, vb,
      M1P_, C_, C_, 0);
  // 3. scores via split MFMA (attn overwrites xa region; xa dead)
  scores_mfma_kernel<<<B_ * H_, 256, 0, stream>>>(qhi, qlo, attn);
  // 4. softmax
  softmax_kernel<<<(B_ * H_ * N_) / 4, 256, 0, stream>>>(attn);
  // 5. sigma per (b,h) — hybrid-aggregated parallel radix select
  run_select(attn, N_ * N_, KASC_ATTN, 16, sig);
  // 6. attn @ v via MFMA (threshold folded into staging) -> aout bf16
  attn_v_mfma_kernel<<<B_ * H_, 256, 0, stream>>>(attn, sig, vb, aout);
  // 7. token_rank (thresholded diag) + stable order
  token_rank_kernel<<<B_, 256, 0, stream>>>(attn, sig, tr);
  order_kernel<<<B_, 256, 0, stream>>>(tr, ord);
  // 8. x1 = x + aout @ proj_w.T + proj_b (fp32)
  gemm_bf16_kernel<<<dim3(C_ / 128, M1P_ / 128), 256, 0, stream>>>(
      aout, prjwb, projb, x, x1, nullptr, M1_, C_, C_, 0);
  // 9. w gather (threshold folded) + w_sigma + w threshold
  {
    const int total = B_ * H_ * NK_ * NP_;
    w_gather_kernel<<<(total + 255) / 256, 256, 0, stream>>>(attn, sig, ord, wbuf);
    run_select(wbuf, NK_ * NP_, KASC_W, 4, wsig);
    threshold_kernel<<<(total + 255) / 256, 256, 0, stream>>>(wbuf, wsig, total,
                                                              NK_ * NP_);
  }
  // attn now dead -> convert fc1/fc2 weights into tail of region A
  wconv_kernel<<<(MLP_ * C_ + 255) / 256, 256, 0, stream>>>(
      fc1w, fc1wb, MLP_ * C_);
  wconv_kernel<<<(C_ * MLP_ + 255) / 256, 256, 0, stream>>>(
      fc2w, fc2wb, C_ * MLP_);
  // 10. x_prop + assemble x2 (d_out)
  xprop_kernel<<<dim3(N2_, B_), 256, 0, stream>>>(x1, wbuf, ord, x2);
  // 11. LN2 -> bf16 (pad rows zeroed)
  ln_bf16_kernel<<<M2P_, 256, 0, stream>>>(x2, n2w, n2b, h2, nullptr, M2_);
  // 12. fc1 + bias + gelu -> bf16
  gemm_bf16_kernel<<<dim3(MLP_ / 128, M2P_ / 128), 256, 0, stream>>>(
      h2, fc1wb, fc1b, nullptr, nullptr, fc1h, M2P_, MLP_, C_, 1);
  // 13. out = x2 + fc1h @ fc2_w.T + fc2_b (in-place on d_out)
  gemm_bf16_kernel<<<dim3(C_ / 128, M2P_ / 128), 256, 0, stream>>>(
      fc1h, fc2wb, fc2b, x2, outp, nullptr, M2_, C_, MLP_, 0);
}